// Round 1
// baseline (7855.267 us; speedup 1.0000x reference)
//
#include <hip/hip_runtime.h>
#include <hip/hip_bf16.h>
#include <math.h>

#define D_MODEL 1024
#define NH      16
#define HD      64
#define T_SEQ   2048
#define B_SZ    4

// ---------------------------------------------------------------------------
// Generic fp32 tiled GEMM with bias: C[M,N] = A[M,K] @ B[K,N] + bias[N]
// BM=BN=64, BK=16, 256 threads, 4x4 micro-tile per thread.
// lda/ldb/ldc passed so GEMM2 can read the attention output out of the
// strided Q-slot of the QKV buffer.
// ---------------------------------------------------------------------------
#define BM 64
#define BN 64
#define BK 16

__global__ __launch_bounds__(256) void gemm_bias(
    const float* __restrict__ A, const float* __restrict__ B,
    const float* __restrict__ bias, float* __restrict__ C,
    int M, int N, int K, int lda, int ldb, int ldc)
{
    __shared__ float As[BK][BM];      // As[k][m]
    __shared__ float Bs[BK][BN];      // Bs[k][n]

    const int tid = threadIdx.x;
    const int tx = tid & 15;          // 0..15 -> N direction
    const int ty = tid >> 4;          // 0..15 -> M direction
    const int row0 = blockIdx.y * BM;
    const int col0 = blockIdx.x * BN;

    float acc[4][4] = {};

    for (int k0 = 0; k0 < K; k0 += BK) {
        // Load A tile: 64 rows x 16 k — 1024 elems, 4 per thread.
        #pragma unroll
        for (int i = 0; i < 4; ++i) {
            int e = tid + i * 256;
            int r = e >> 4;           // 0..63
            int c = e & 15;           // 0..15
            As[c][r] = A[(size_t)(row0 + r) * lda + (k0 + c)];
        }
        // Load B tile: 16 k x 64 cols — coalesced 64-wide rows.
        #pragma unroll
        for (int i = 0; i < 4; ++i) {
            int e = tid + i * 256;
            int r = e >> 6;           // 0..15
            int c = e & 63;           // 0..63
            Bs[r][c] = B[(size_t)(k0 + r) * ldb + (col0 + c)];
        }
        __syncthreads();

        #pragma unroll
        for (int kk = 0; kk < BK; ++kk) {
            float a[4], b[4];
            #pragma unroll
            for (int i = 0; i < 4; ++i) a[i] = As[kk][ty * 4 + i];
            #pragma unroll
            for (int j = 0; j < 4; ++j) b[j] = Bs[kk][tx * 4 + j];
            #pragma unroll
            for (int i = 0; i < 4; ++i)
                #pragma unroll
                for (int j = 0; j < 4; ++j)
                    acc[i][j] += a[i] * b[j];
        }
        __syncthreads();
    }

    #pragma unroll
    for (int i = 0; i < 4; ++i) {
        int r = row0 + ty * 4 + i;
        #pragma unroll
        for (int j = 0; j < 4; ++j) {
            int c = col0 + tx * 4 + j;
            C[(size_t)r * ldc + c] = acc[i][j] + bias[c];
        }
    }
}

// ---------------------------------------------------------------------------
// Causal attention, one block per (b, h, q-row). Two-pass softmax with the
// score row staged in LDS (max T=2048 floats = 8 KB). Output written IN
// PLACE over the Q slot of the QKV buffer (safe: each block is the only
// reader of its own Q row, and reads it before writing).
// qkv layout: [b*T + t][s*1024 + h*64 + d], row stride 3072, s in {q,k,v}.
// ---------------------------------------------------------------------------
__global__ __launch_bounds__(256) void attn_kernel(float* __restrict__ qkv)
{
    const int bid = blockIdx.x;            // q + T*(h + NH*b)
    const int qi  = bid & (T_SEQ - 1);
    const int hb  = bid >> 11;
    const int h   = hb & (NH - 1);
    const int b   = hb >> 4;
    const int tid = threadIdx.x;

    __shared__ float s[T_SEQ];
    __shared__ float qs[HD];
    __shared__ float red[256];

    const size_t rowq = ((size_t)(b * T_SEQ + qi) * 3) * (size_t)D_MODEL + h * HD;

    if (tid < HD) qs[tid] = qkv[rowq + tid];
    __syncthreads();

    const int   nk    = qi + 1;
    const float scale = 0.125f;            // 1/sqrt(64)

    // Pass 1: scores + local max
    float lmax = -1e30f;
    for (int k = tid; k < nk; k += 256) {
        const size_t kb = ((size_t)(b * T_SEQ + k) * 3 + 1) * (size_t)D_MODEL + h * HD;
        float acc = 0.f;
        #pragma unroll
        for (int d = 0; d < HD; ++d) acc += qs[d] * qkv[kb + d];
        acc *= scale;
        s[k] = acc;
        lmax = fmaxf(lmax, acc);
    }
    red[tid] = lmax;
    __syncthreads();
    for (int off = 128; off >= 1; off >>= 1) {
        if (tid < off) red[tid] = fmaxf(red[tid], red[tid + off]);
        __syncthreads();
    }
    const float m = red[0];
    __syncthreads();

    // Pass 2: exp + local sum
    float lsum = 0.f;
    for (int k = tid; k < nk; k += 256) {
        float e = __expf(s[k] - m);
        s[k] = e;
        lsum += e;
    }
    red[tid] = lsum;
    __syncthreads();
    for (int off = 128; off >= 1; off >>= 1) {
        if (tid < off) red[tid] += red[tid + off];
        __syncthreads();
    }
    const float inv = 1.f / red[0];
    __syncthreads();

    // PV: 4 k-groups x 64 dims
    const int d = tid & (HD - 1);
    const int g = tid >> 6;
    float acc = 0.f;
    for (int k = g; k < nk; k += 4) {
        const size_t vb = ((size_t)(b * T_SEQ + k) * 3 + 2) * (size_t)D_MODEL + h * HD;
        acc += s[k] * qkv[vb + d];
    }
    __syncthreads();
    red[tid] = acc;
    __syncthreads();
    if (tid < HD) {
        float o = (red[tid] + red[tid + 64] + red[tid + 128] + red[tid + 192]) * inv;
        qkv[rowq + tid] = o;
    }
}

// ---------------------------------------------------------------------------
extern "C" void kernel_launch(void* const* d_in, const int* in_sizes, int n_in,
                              void* d_out, int out_size, void* d_ws, size_t ws_size,
                              hipStream_t stream)
{
    const float* x      = (const float*)d_in[0];
    const float* w_qkv  = (const float*)d_in[1];
    const float* b_qkv  = (const float*)d_in[2];
    const float* w_proj = (const float*)d_in[3];
    const float* b_proj = (const float*)d_in[4];
    float* out = (float*)d_out;
    float* qkv = (float*)d_ws;   // 8192 x 3072 fp32 = 100.7 MB

    const int M  = B_SZ * T_SEQ;       // 8192
    const int N1 = 3 * D_MODEL;        // 3072
    const int K  = D_MODEL;            // 1024

    // QKV projection
    dim3 g1(N1 / BN, M / BM);
    gemm_bias<<<g1, 256, 0, stream>>>(x, w_qkv, b_qkv, qkv, M, N1, K, K, N1, N1);

    // Attention (writes output over the Q slot of qkv)
    attn_kernel<<<dim3(B_SZ * NH * T_SEQ), 256, 0, stream>>>(qkv);

    // Output projection: A = Q-slot of qkv (lda = 3072)
    dim3 g2(D_MODEL / BN, M / BM);
    gemm_bias<<<g2, 256, 0, stream>>>(qkv, w_proj, b_proj, out, M, D_MODEL, K, N1, D_MODEL, D_MODEL);
}

// Round 2
// 1438.577 us; speedup vs baseline: 5.4604x; 5.4604x over previous
//
#include <hip/hip_runtime.h>
#include <hip/hip_bf16.h>
#include <math.h>

#define D_MODEL 1024
#define NH      16
#define HD      64
#define T_SEQ   2048
#define B_SZ    4

typedef __bf16 bf16x8 __attribute__((ext_vector_type(8)));
typedef float  f32x4  __attribute__((ext_vector_type(4)));

// ---------------------------------------------------------------------------
// fp32 tiled GEMM with bias (unchanged from R1): C[M,N] = A[M,K]@B[K,N]+bias
// ---------------------------------------------------------------------------
#define BM 64
#define BN 64
#define BK 16

__global__ __launch_bounds__(256) void gemm_bias(
    const float* __restrict__ A, const float* __restrict__ B,
    const float* __restrict__ bias, float* __restrict__ C,
    int M, int N, int K, int lda, int ldb, int ldc)
{
    __shared__ float As[BK][BM];
    __shared__ float Bs[BK][BN];

    const int tid = threadIdx.x;
    const int tx = tid & 15;
    const int ty = tid >> 4;
    const int row0 = blockIdx.y * BM;
    const int col0 = blockIdx.x * BN;

    float acc[4][4] = {};

    for (int k0 = 0; k0 < K; k0 += BK) {
        #pragma unroll
        for (int i = 0; i < 4; ++i) {
            int e = tid + i * 256;
            int r = e >> 4;
            int c = e & 15;
            As[c][r] = A[(size_t)(row0 + r) * lda + (k0 + c)];
        }
        #pragma unroll
        for (int i = 0; i < 4; ++i) {
            int e = tid + i * 256;
            int r = e >> 6;
            int c = e & 63;
            Bs[r][c] = B[(size_t)(k0 + r) * ldb + (col0 + c)];
        }
        __syncthreads();

        #pragma unroll
        for (int kk = 0; kk < BK; ++kk) {
            float a[4], b[4];
            #pragma unroll
            for (int i = 0; i < 4; ++i) a[i] = As[kk][ty * 4 + i];
            #pragma unroll
            for (int j = 0; j < 4; ++j) b[j] = Bs[kk][tx * 4 + j];
            #pragma unroll
            for (int i = 0; i < 4; ++i)
                #pragma unroll
                for (int j = 0; j < 4; ++j)
                    acc[i][j] += a[i] * b[j];
        }
        __syncthreads();
    }

    #pragma unroll
    for (int i = 0; i < 4; ++i) {
        int r = row0 + ty * 4 + i;
        #pragma unroll
        for (int j = 0; j < 4; ++j) {
            int c = col0 + tx * 4 + j;
            C[(size_t)r * ldc + c] = acc[i][j] + bias[c];
        }
    }
}

// ---------------------------------------------------------------------------
// MFMA flash attention.
// Block = 256 threads = 4 waves; block handles (b, h, q-tile of 64 rows);
// wave w owns q-rows [qbase, qbase+16).  k-tiles of 32 positions.
//
// mfma_f32_16x16x32_bf16 layouts (verified, learn_hip m89/m91):
//   A: row = lane%16,           k = 8*(lane/16)+i   (bf16x8)
//   B: col = lane%16,           k = 8*(lane/16)+i   (bf16x8)
//   D: col = lane%16,           row = 4*(lane/16)+reg (f32x4)
//
// S = Q*K^T  : A=Q frag (regs), B=K^T frag from LDS Ks[kpos][dim]
// O += P*V   : A=P frag from LDS Ps, B=V frag from LDS Vt[dim][kpos] (transposed)
// Output written in place over the Q slot of the qkv buffer.
// ---------------------------------------------------------------------------
__device__ __forceinline__ bf16x8 cvt8(float4 a, float4 b) {
    bf16x8 v;
    v[0]=(__bf16)a.x; v[1]=(__bf16)a.y; v[2]=(__bf16)a.z; v[3]=(__bf16)a.w;
    v[4]=(__bf16)b.x; v[5]=(__bf16)b.y; v[6]=(__bf16)b.z; v[7]=(__bf16)b.w;
    return v;
}

__global__ __launch_bounds__(256) void attn_mfma(float* __restrict__ qkv)
{
    const int bix  = blockIdx.x;
    const int qt   = bix & 31;
    const int h    = (bix >> 5) & 15;
    const int b    = bix >> 9;
    const int tid  = threadIdx.x;
    const int wid  = tid >> 6;
    const int lane = tid & 63;
    const int g    = lane >> 4;      // 0..3
    const int n    = lane & 15;      // 0..15

    const int q0    = qt * 64;
    const int qbase = q0 + wid * 16;
    const int nkt   = (q0 >> 5) + 2;          // k-tiles covering [0, q0+64)

    __shared__ __bf16 Ks[32][72];             // [kpos][dim], +8 pad (2-way max)
    __shared__ __bf16 Vt[64][40];             // [dim][kpos], col-block swizzled
    __shared__ __bf16 Ps[4][16][40];          // per-wave P tile [qrow][kpos]

    // ---- Q fragments (held in regs for whole kernel), 2 chunks of K=32 ----
    bf16x8 qa[2];
    {
        const size_t qrow = (size_t)(b * T_SEQ + qbase + n) * (3 * D_MODEL) + (size_t)h * HD;
        #pragma unroll
        for (int cc = 0; cc < 2; ++cc) {
            const float* p = qkv + qrow + cc * 32 + g * 8;
            float4 f0 = *(const float4*)p;
            float4 f1 = *(const float4*)(p + 4);
            qa[cc] = cvt8(f0, f1);
        }
    }

    f32x4 o[4] = {};                 // o[nt][r] = O[qbase+4g+r][nt*16+n]
    float mrow[4] = {-INFINITY, -INFINITY, -INFINITY, -INFINITY};
    float lrow[4] = {0.f, 0.f, 0.f, 0.f};

    const int skp = tid >> 3;        // staging: kpos row 0..31
    const int sc8 = (tid & 7) * 8;   // staging: dim start
    const int scd = tid & 7;         // dim>>3 for this thread's 8 dims

    for (int kt = 0; kt < nkt; ++kt) {
        const int kbase = kt * 32;

        // ---- stage K tile (row-major bf16) ----
        {
            const float* p = qkv + ((size_t)(b * T_SEQ + kbase + skp) * 3 + 1) * D_MODEL
                             + (size_t)h * HD + sc8;
            float4 f0 = *(const float4*)p;
            float4 f1 = *(const float4*)(p + 4);
            *(bf16x8*)&Ks[skp][sc8] = cvt8(f0, f1);
        }
        // ---- stage V tile transposed: Vt[dim][kpos], kpos block ^ (dim>>3)&3 ----
        {
            const float* p = qkv + ((size_t)(b * T_SEQ + kbase + skp) * 3 + 2) * D_MODEL
                             + (size_t)h * HD + sc8;
            float4 f0 = *(const float4*)p;
            float4 f1 = *(const float4*)(p + 4);
            const int kps = skp ^ ((scd & 3) << 3);
            Vt[sc8 + 0][kps] = (__bf16)f0.x;
            Vt[sc8 + 1][kps] = (__bf16)f0.y;
            Vt[sc8 + 2][kps] = (__bf16)f0.z;
            Vt[sc8 + 3][kps] = (__bf16)f0.w;
            Vt[sc8 + 4][kps] = (__bf16)f1.x;
            Vt[sc8 + 5][kps] = (__bf16)f1.y;
            Vt[sc8 + 6][kps] = (__bf16)f1.z;
            Vt[sc8 + 7][kps] = (__bf16)f1.w;
        }
        __syncthreads();

        // ---- S = Q K^T  (two 16-col subtiles, K-loop over 2 dim-chunks) ----
        f32x4 s0 = {0.f, 0.f, 0.f, 0.f};
        f32x4 s1 = {0.f, 0.f, 0.f, 0.f};
        #pragma unroll
        for (int cc = 0; cc < 2; ++cc) {
            bf16x8 k0 = *(const bf16x8*)&Ks[n][cc * 32 + g * 8];
            bf16x8 k1 = *(const bf16x8*)&Ks[16 + n][cc * 32 + g * 8];
            s0 = __builtin_amdgcn_mfma_f32_16x16x32_bf16(qa[cc], k0, s0, 0, 0, 0);
            s1 = __builtin_amdgcn_mfma_f32_16x16x32_bf16(qa[cc], k1, s1, 0, 0, 0);
        }

        // ---- online softmax (per q-row; rows 4g+r live in reg r across 16 lanes) ----
        #pragma unroll
        for (int r = 0; r < 4; ++r) {
            const int qrow = qbase + 4 * g + r;
            float v0 = s0[r] * 0.125f;
            float v1 = s1[r] * 0.125f;
            if (kbase + n > qrow)      v0 = -INFINITY;   // causal mask
            if (kbase + 16 + n > qrow) v1 = -INFINITY;

            float tm = fmaxf(v0, v1);
            #pragma unroll
            for (int off = 1; off < 16; off <<= 1)
                tm = fmaxf(tm, __shfl_xor(tm, off));

            const float mnew = fmaxf(mrow[r], tm);
            const float corr = __expf(mrow[r] - mnew);
            mrow[r] = mnew;

            const float p0 = __expf(v0 - mnew);
            const float p1 = __expf(v1 - mnew);
            float rs = p0 + p1;
            #pragma unroll
            for (int off = 1; off < 16; off <<= 1)
                rs += __shfl_xor(rs, off);

            lrow[r] = lrow[r] * corr + rs;
            o[0][r] *= corr; o[1][r] *= corr; o[2][r] *= corr; o[3][r] *= corr;

            Ps[wid][4 * g + r][n]      = (__bf16)p0;
            Ps[wid][4 * g + r][16 + n] = (__bf16)p1;
        }
        __syncthreads();

        // ---- O += P V ----
        {
            bf16x8 pa = *(const bf16x8*)&Ps[wid][n][g * 8];
            #pragma unroll
            for (int nt = 0; nt < 4; ++nt) {
                const int d  = nt * 16 + n;
                const int cb = g ^ ((d >> 3) & 3);
                bf16x8 vb = *(const bf16x8*)&Vt[d][cb * 8];
                o[nt] = __builtin_amdgcn_mfma_f32_16x16x32_bf16(pa, vb, o[nt], 0, 0, 0);
            }
        }
        __syncthreads();
    }

    // ---- normalize and store over the Q slot ----
    float inv[4];
    #pragma unroll
    for (int r = 0; r < 4; ++r) inv[r] = 1.f / lrow[r];

    const size_t obase = (size_t)(b * T_SEQ + qbase) * (3 * D_MODEL) + (size_t)h * HD;
    #pragma unroll
    for (int nt = 0; nt < 4; ++nt)
        #pragma unroll
        for (int r = 0; r < 4; ++r)
            qkv[obase + (size_t)(4 * g + r) * (3 * D_MODEL) + nt * 16 + n] = o[nt][r] * inv[r];
}

// ---------------------------------------------------------------------------
extern "C" void kernel_launch(void* const* d_in, const int* in_sizes, int n_in,
                              void* d_out, int out_size, void* d_ws, size_t ws_size,
                              hipStream_t stream)
{
    const float* x      = (const float*)d_in[0];
    const float* w_qkv  = (const float*)d_in[1];
    const float* b_qkv  = (const float*)d_in[2];
    const float* w_proj = (const float*)d_in[3];
    const float* b_proj = (const float*)d_in[4];
    float* out = (float*)d_out;
    float* qkv = (float*)d_ws;   // 8192 x 3072 fp32 = 100.7 MB

    const int M  = B_SZ * T_SEQ;       // 8192
    const int N1 = 3 * D_MODEL;        // 3072
    const int K  = D_MODEL;            // 1024

    // QKV projection
    dim3 g1(N1 / BN, M / BM);
    gemm_bias<<<g1, 256, 0, stream>>>(x, w_qkv, b_qkv, qkv, M, N1, K, K, N1, N1);

    // Flash attention (writes output over the Q slot of qkv)
    attn_mfma<<<dim3(B_SZ * NH * (T_SEQ / 64)), 256, 0, stream>>>(qkv);

    // Output projection: A = Q-slot of qkv (lda = 3072)
    dim3 g2(D_MODEL / BN, M / BM);
    gemm_bias<<<g2, 256, 0, stream>>>(qkv, w_proj, b_proj, out, M, D_MODEL, K, N1, D_MODEL, D_MODEL);
}

// Round 3
// 440.192 us; speedup vs baseline: 17.8451x; 3.2681x over previous
//
#include <hip/hip_runtime.h>
#include <hip/hip_bf16.h>
#include <math.h>

#define D_MODEL 1024
#define NH      16
#define HD      64
#define T_SEQ   2048
#define B_SZ    4
#define M_ROWS  (B_SZ * T_SEQ)       // 8192
#define N_QKV   (3 * D_MODEL)        // 3072

typedef __bf16 bf16x8 __attribute__((ext_vector_type(8)));
typedef float  f32x4  __attribute__((ext_vector_type(4)));

__device__ __forceinline__ bf16x8 cvt8(float4 a, float4 b) {
    bf16x8 v;
    v[0]=(__bf16)a.x; v[1]=(__bf16)a.y; v[2]=(__bf16)a.z; v[3]=(__bf16)a.w;
    v[4]=(__bf16)b.x; v[5]=(__bf16)b.y; v[6]=(__bf16)b.z; v[7]=(__bf16)b.w;
    return v;
}

__device__ __forceinline__ void gload_lds16(const __bf16* g, __bf16* l) {
    __builtin_amdgcn_global_load_lds(
        (const __attribute__((address_space(1))) void*)g,
        (__attribute__((address_space(3))) void*)l, 16, 0, 0);
}

// ---------------------------------------------------------------------------
// fp32 -> bf16 elementwise convert, 8 elems/thread
// ---------------------------------------------------------------------------
__global__ __launch_bounds__(256) void cvt_bf16(const float* __restrict__ in,
                                                __bf16* __restrict__ out, int n8)
{
    int i = blockIdx.x * 256 + threadIdx.x;
    if (i < n8) {
        float4 a = ((const float4*)in)[2 * i];
        float4 b = ((const float4*)in)[2 * i + 1];
        ((bf16x8*)out)[i] = cvt8(a, b);
    }
}

// ---------------------------------------------------------------------------
// Transpose + convert: W[R][C] fp32 -> WT[C][R] bf16.  32x32 LDS tiles.
// ---------------------------------------------------------------------------
__global__ __launch_bounds__(256) void transpose_cvt(
    const float* __restrict__ W, __bf16* __restrict__ WT, int R, int C)
{
    __shared__ float t[32][33];
    const int tr0 = blockIdx.y * 32, tc0 = blockIdx.x * 32;
    const int lr = threadIdx.x >> 5, lc = threadIdx.x & 31;
    #pragma unroll
    for (int i = 0; i < 4; ++i)
        t[lr + i * 8][lc] = W[(size_t)(tr0 + lr + i * 8) * C + tc0 + lc];
    __syncthreads();
    #pragma unroll
    for (int i = 0; i < 4; ++i)
        WT[(size_t)(tc0 + lr + i * 8) * R + tr0 + lc] = (__bf16)t[lc][lr + i * 8];
}

// ---------------------------------------------------------------------------
// bf16 MFMA GEMM (m97 structure): C[M][N] = A[M][K] @ BT[N][K]^T + bias[N]
// 128x128 tile, BK=32, 256 threads = 4 waves (2x2), 4x4 16x16x32 frags/wave.
// global_load_lds width=16 into linear LDS [128][32]; XCD-bijective swizzle.
// OUT_BF16: 1 -> __bf16 C, 0 -> float C.
// ---------------------------------------------------------------------------
template<int OUT_BF16>
__global__ __launch_bounds__(256) void gemm_mfma(
    const __bf16* __restrict__ A, const __bf16* __restrict__ BT,
    const float* __restrict__ bias, void* __restrict__ Cout,
    int M, int N, int K)
{
    __shared__ __bf16 As[128 * 32];
    __shared__ __bf16 Bs[128 * 32];

    const int nbn = N >> 7;
    const int nwg = gridDim.x;
    int bid = blockIdx.x;
    bid = (bid & 7) * (nwg >> 3) + (bid >> 3);       // XCD swizzle (nwg % 8 == 0)
    const int tm = bid / nbn, tn = bid % nbn;
    const int row0 = tm << 7, col0 = tn << 7;

    const int tid  = threadIdx.x;
    const int wid  = tid >> 6, lane = tid & 63;
    const int wm   = wid >> 1, wn = wid & 1;
    const int g    = lane >> 4, r16 = lane & 15;

    // staging decomposition: each wave issues 2x 1KB segments per operand
    const int srow = lane >> 2;          // 0..15 within segment
    const int skk  = (lane & 3) * 8;     // k offset 0,8,16,24

    f32x4 acc[4][4] = {};

    for (int k0 = 0; k0 < K; k0 += 32) {
        #pragma unroll
        for (int i = 0; i < 2; ++i) {
            const int seg = wid * 2 + i;                 // 0..7 -> 16 rows each
            const int row = seg * 16 + srow;
            gload_lds16(A  + (size_t)(row0 + row) * K + k0 + skk, As + seg * 512);
            gload_lds16(BT + (size_t)(col0 + row) * K + k0 + skk, Bs + seg * 512);
        }
        __syncthreads();                                 // drain loads + barrier

        bf16x8 af[4], bfr[4];
        #pragma unroll
        for (int mt = 0; mt < 4; ++mt)
            af[mt] = *(const bf16x8*)&As[(wm * 64 + mt * 16 + r16) * 32 + g * 8];
        #pragma unroll
        for (int nt = 0; nt < 4; ++nt)
            bfr[nt] = *(const bf16x8*)&Bs[(wn * 64 + nt * 16 + r16) * 32 + g * 8];
        #pragma unroll
        for (int mt = 0; mt < 4; ++mt)
            #pragma unroll
            for (int nt = 0; nt < 4; ++nt)
                acc[mt][nt] = __builtin_amdgcn_mfma_f32_16x16x32_bf16(
                    af[mt], bfr[nt], acc[mt][nt], 0, 0, 0);
        __syncthreads();                                 // reads done before next stage
    }

    #pragma unroll
    for (int mt = 0; mt < 4; ++mt) {
        #pragma unroll
        for (int nt = 0; nt < 4; ++nt) {
            const int col = col0 + wn * 64 + nt * 16 + r16;
            const float bv = bias[col];
            #pragma unroll
            for (int j = 0; j < 4; ++j) {
                const int row = row0 + wm * 64 + mt * 16 + g * 4 + j;
                const float v = acc[mt][nt][j] + bv;
                if (OUT_BF16)
                    ((__bf16*)Cout)[(size_t)row * N + col] = (__bf16)v;
                else
                    ((float*)Cout)[(size_t)row * N + col] = v;
            }
        }
    }
}

// ---------------------------------------------------------------------------
// MFMA flash attention (bf16 in / bf16 out).
// Block = 4 waves, one (b,h,64-row q-tile); wave owns 16 q-rows; 32-wide k-tiles.
// qkvb: [b*T+t][3072] bf16 (q|k|v slots).  Writes attn_out [b*T+t][1024] bf16.
// ---------------------------------------------------------------------------
__global__ __launch_bounds__(256) void attn_mfma(
    const __bf16* __restrict__ qkvb, __bf16* __restrict__ attn_out)
{
    const int bix  = blockIdx.x;
    const int qt   = bix & 31;
    const int h    = (bix >> 5) & 15;
    const int b    = bix >> 9;
    const int tid  = threadIdx.x;
    const int wid  = tid >> 6;
    const int lane = tid & 63;
    const int g    = lane >> 4;
    const int n    = lane & 15;

    const int q0    = qt * 64;
    const int qbase = q0 + wid * 16;
    const int nkt   = (q0 >> 5) + 2;

    __shared__ __bf16 Ks[32][72];
    __shared__ __bf16 Vt[64][40];
    __shared__ __bf16 Ps[4][16][40];

    bf16x8 qa[2];
    {
        const size_t qrow = (size_t)(b * T_SEQ + qbase + n) * N_QKV + (size_t)h * HD;
        qa[0] = *(const bf16x8*)&qkvb[qrow + g * 8];
        qa[1] = *(const bf16x8*)&qkvb[qrow + 32 + g * 8];
    }

    f32x4 o[4] = {};
    float mrow[4] = {-INFINITY, -INFINITY, -INFINITY, -INFINITY};
    float lrow[4] = {0.f, 0.f, 0.f, 0.f};

    const int skp = tid >> 3;
    const int sc8 = (tid & 7) * 8;
    const int scd = tid & 7;

    for (int kt = 0; kt < nkt; ++kt) {
        const int kbase = kt * 32;

        *(bf16x8*)&Ks[skp][sc8] = *(const bf16x8*)&qkvb[
            (size_t)(b * T_SEQ + kbase + skp) * N_QKV + D_MODEL + (size_t)h * HD + sc8];
        {
            bf16x8 v = *(const bf16x8*)&qkvb[
                (size_t)(b * T_SEQ + kbase + skp) * N_QKV + 2 * D_MODEL + (size_t)h * HD + sc8];
            const int kps = skp ^ ((scd & 3) << 3);
            #pragma unroll
            for (int j = 0; j < 8; ++j) Vt[sc8 + j][kps] = v[j];
        }
        __syncthreads();

        f32x4 s0 = {0.f, 0.f, 0.f, 0.f};
        f32x4 s1 = {0.f, 0.f, 0.f, 0.f};
        #pragma unroll
        for (int cc = 0; cc < 2; ++cc) {
            bf16x8 k0 = *(const bf16x8*)&Ks[n][cc * 32 + g * 8];
            bf16x8 k1 = *(const bf16x8*)&Ks[16 + n][cc * 32 + g * 8];
            s0 = __builtin_amdgcn_mfma_f32_16x16x32_bf16(qa[cc], k0, s0, 0, 0, 0);
            s1 = __builtin_amdgcn_mfma_f32_16x16x32_bf16(qa[cc], k1, s1, 0, 0, 0);
        }

        #pragma unroll
        for (int r = 0; r < 4; ++r) {
            const int qrow = qbase + 4 * g + r;
            float v0 = s0[r] * 0.125f;
            float v1 = s1[r] * 0.125f;
            if (kbase + n > qrow)      v0 = -INFINITY;
            if (kbase + 16 + n > qrow) v1 = -INFINITY;

            float tm = fmaxf(v0, v1);
            #pragma unroll
            for (int off = 1; off < 16; off <<= 1)
                tm = fmaxf(tm, __shfl_xor(tm, off));

            const float mnew = fmaxf(mrow[r], tm);
            const float corr = __expf(mrow[r] - mnew);
            mrow[r] = mnew;

            const float p0 = __expf(v0 - mnew);
            const float p1 = __expf(v1 - mnew);
            float rs = p0 + p1;
            #pragma unroll
            for (int off = 1; off < 16; off <<= 1)
                rs += __shfl_xor(rs, off);

            lrow[r] = lrow[r] * corr + rs;
            o[0][r] *= corr; o[1][r] *= corr; o[2][r] *= corr; o[3][r] *= corr;

            Ps[wid][4 * g + r][n]      = (__bf16)p0;
            Ps[wid][4 * g + r][16 + n] = (__bf16)p1;
        }
        __syncthreads();

        {
            bf16x8 pa = *(const bf16x8*)&Ps[wid][n][g * 8];
            #pragma unroll
            for (int nt = 0; nt < 4; ++nt) {
                const int d  = nt * 16 + n;
                const int cb = g ^ ((d >> 3) & 3);
                bf16x8 vb = *(const bf16x8*)&Vt[d][cb * 8];
                o[nt] = __builtin_amdgcn_mfma_f32_16x16x32_bf16(pa, vb, o[nt], 0, 0, 0);
            }
        }
        __syncthreads();
    }

    float inv[4];
    #pragma unroll
    for (int r = 0; r < 4; ++r) inv[r] = 1.f / lrow[r];

    const size_t obase = (size_t)(b * T_SEQ + qbase) * D_MODEL + (size_t)h * HD;
    #pragma unroll
    for (int nt = 0; nt < 4; ++nt)
        #pragma unroll
        for (int r = 0; r < 4; ++r)
            attn_out[obase + (size_t)(4 * g + r) * D_MODEL + nt * 16 + n]
                = (__bf16)(o[nt][r] * inv[r]);
}

// ---------------------------------------------------------------------------
extern "C" void kernel_launch(void* const* d_in, const int* in_sizes, int n_in,
                              void* d_out, int out_size, void* d_ws, size_t ws_size,
                              hipStream_t stream)
{
    const float* x      = (const float*)d_in[0];
    const float* w_qkv  = (const float*)d_in[1];
    const float* b_qkv  = (const float*)d_in[2];
    const float* w_proj = (const float*)d_in[3];
    const float* b_proj = (const float*)d_in[4];
    float* out = (float*)d_out;

    // workspace layout (bf16 unless noted)
    char* ws = (char*)d_ws;
    __bf16* qkvb   = (__bf16*)ws;                              // 8192x3072
    __bf16* xb     = (__bf16*)(ws + (size_t)M_ROWS * N_QKV * 2);          // 8192x1024
    __bf16* wqkvT  = (__bf16*)(ws + (size_t)M_ROWS * N_QKV * 2
                                  + (size_t)M_ROWS * D_MODEL * 2);        // 3072x1024
    __bf16* wprojT = wqkvT + (size_t)N_QKV * D_MODEL;                     // 1024x1024
    __bf16* aout   = wprojT + (size_t)D_MODEL * D_MODEL;                  // 8192x1024

    // 1. convert x
    cvt_bf16<<<dim3(M_ROWS * D_MODEL / 8 / 256), 256, 0, stream>>>(
        x, xb, M_ROWS * D_MODEL / 8);
    // 2. transpose-convert weights -> [N][K]
    transpose_cvt<<<dim3(N_QKV / 32, D_MODEL / 32), 256, 0, stream>>>(
        w_qkv, wqkvT, D_MODEL, N_QKV);
    transpose_cvt<<<dim3(D_MODEL / 32, D_MODEL / 32), 256, 0, stream>>>(
        w_proj, wprojT, D_MODEL, D_MODEL);

    // 3. QKV projection (bf16 out)
    gemm_mfma<1><<<dim3((M_ROWS / 128) * (N_QKV / 128)), 256, 0, stream>>>(
        xb, wqkvT, b_qkv, qkvb, M_ROWS, N_QKV, D_MODEL);

    // 4. flash attention
    attn_mfma<<<dim3(B_SZ * NH * (T_SEQ / 64)), 256, 0, stream>>>(qkvb, aout);

    // 5. output projection (f32 out)
    gemm_mfma<0><<<dim3((M_ROWS / 128) * (D_MODEL / 128)), 256, 0, stream>>>(
        aout, wprojT, b_proj, out, M_ROWS, D_MODEL, D_MODEL);
}

// Round 4
// 275.207 us; speedup vs baseline: 28.5431x; 1.5995x over previous
//
#include <hip/hip_runtime.h>
#include <hip/hip_bf16.h>
#include <math.h>

#define D_MODEL 1024
#define NH      16
#define HD      64
#define T_SEQ   2048
#define B_SZ    4
#define M_ROWS  (B_SZ * T_SEQ)       // 8192
#define N_QKV   (3 * D_MODEL)        // 3072

typedef __bf16 bf16x8 __attribute__((ext_vector_type(8)));
typedef __bf16 bf16x4 __attribute__((ext_vector_type(4)));
typedef float  f32x4  __attribute__((ext_vector_type(4)));

__device__ __forceinline__ bf16x8 cvt8(float4 a, float4 b) {
    bf16x8 v;
    v[0]=(__bf16)a.x; v[1]=(__bf16)a.y; v[2]=(__bf16)a.z; v[3]=(__bf16)a.w;
    v[4]=(__bf16)b.x; v[5]=(__bf16)b.y; v[6]=(__bf16)b.z; v[7]=(__bf16)b.w;
    return v;
}

__device__ __forceinline__ void gload_lds16(const __bf16* g, __bf16* l) {
    __builtin_amdgcn_global_load_lds(
        (const __attribute__((address_space(1))) void*)g,
        (__attribute__((address_space(3))) void*)l, 16, 0, 0);
}

// ---------------------------------------------------------------------------
// fp32 -> bf16 elementwise convert, 8 elems/thread
// ---------------------------------------------------------------------------
__global__ __launch_bounds__(256) void cvt_bf16(const float* __restrict__ in,
                                                __bf16* __restrict__ out, int n8)
{
    int i = blockIdx.x * 256 + threadIdx.x;
    if (i < n8) {
        float4 a = ((const float4*)in)[2 * i];
        float4 b = ((const float4*)in)[2 * i + 1];
        ((bf16x8*)out)[i] = cvt8(a, b);
    }
}

// ---------------------------------------------------------------------------
// Transpose + convert: W[R][C] fp32 -> WT[C][R] bf16.  32x32 LDS tiles.
// ---------------------------------------------------------------------------
__global__ __launch_bounds__(256) void transpose_cvt(
    const float* __restrict__ W, __bf16* __restrict__ WT, int R, int C)
{
    __shared__ float t[32][33];
    const int tr0 = blockIdx.y * 32, tc0 = blockIdx.x * 32;
    const int lr = threadIdx.x >> 5, lc = threadIdx.x & 31;
    #pragma unroll
    for (int i = 0; i < 4; ++i)
        t[lr + i * 8][lc] = W[(size_t)(tr0 + lr + i * 8) * C + tc0 + lc];
    __syncthreads();
    #pragma unroll
    for (int i = 0; i < 4; ++i)
        WT[(size_t)(tc0 + lr + i * 8) * R + tr0 + lc] = (__bf16)t[lc][lr + i * 8];
}

// ---------------------------------------------------------------------------
// bf16 MFMA GEMM (m97 structure): 128x128 tile, BK=32, 4 waves, 4x4 frags.
// MODE 0: float C, row stride N (output projection).
// MODE 1: qkv split epilogue — cols <2048 (Q|K) -> bf16 qkb stride 2048;
//         cols >=2048 (V) -> transposed vT[b][h][d][t] with packed 8B stores.
// ---------------------------------------------------------------------------
template<int MODE>
__global__ __launch_bounds__(256) void gemm_mfma(
    const __bf16* __restrict__ A, const __bf16* __restrict__ BT,
    const float* __restrict__ bias, void* __restrict__ C0,
    __bf16* __restrict__ vT, int M, int N, int K)
{
    __shared__ __bf16 As[128 * 32];
    __shared__ __bf16 Bs[128 * 32];

    const int nbn = N >> 7;
    const int nwg = gridDim.x;
    int bid = blockIdx.x;
    bid = (bid & 7) * (nwg >> 3) + (bid >> 3);       // XCD swizzle (nwg % 8 == 0)
    const int tm = bid / nbn, tn = bid % nbn;
    const int row0 = tm << 7, col0 = tn << 7;

    const int tid  = threadIdx.x;
    const int wid  = tid >> 6, lane = tid & 63;
    const int wm   = wid >> 1, wn = wid & 1;
    const int g    = lane >> 4, r16 = lane & 15;

    const int srow = lane >> 2;
    const int skk  = (lane & 3) * 8;

    f32x4 acc[4][4] = {};

    for (int k0 = 0; k0 < K; k0 += 32) {
        #pragma unroll
        for (int i = 0; i < 2; ++i) {
            const int seg = wid * 2 + i;
            const int row = seg * 16 + srow;
            gload_lds16(A  + (size_t)(row0 + row) * K + k0 + skk, As + seg * 512);
            gload_lds16(BT + (size_t)(col0 + row) * K + k0 + skk, Bs + seg * 512);
        }
        __syncthreads();

        bf16x8 af[4], bfr[4];
        #pragma unroll
        for (int mt = 0; mt < 4; ++mt)
            af[mt] = *(const bf16x8*)&As[(wm * 64 + mt * 16 + r16) * 32 + g * 8];
        #pragma unroll
        for (int nt = 0; nt < 4; ++nt)
            bfr[nt] = *(const bf16x8*)&Bs[(wn * 64 + nt * 16 + r16) * 32 + g * 8];
        #pragma unroll
        for (int mt = 0; mt < 4; ++mt)
            #pragma unroll
            for (int nt = 0; nt < 4; ++nt)
                acc[mt][nt] = __builtin_amdgcn_mfma_f32_16x16x32_bf16(
                    af[mt], bfr[nt], acc[mt][nt], 0, 0, 0);
        __syncthreads();
    }

    const bool isV = (MODE == 1) && (tn >= 16);      // block-uniform (2048 % 128 == 0)

    #pragma unroll
    for (int mt = 0; mt < 4; ++mt) {
        #pragma unroll
        for (int nt = 0; nt < 4; ++nt) {
            const int col = col0 + wn * 64 + nt * 16 + r16;
            const float bv = bias[col];
            const int rowb = row0 + wm * 64 + mt * 16 + g * 4;
            if (MODE == 0) {
                #pragma unroll
                for (int j = 0; j < 4; ++j)
                    ((float*)C0)[(size_t)(rowb + j) * N + col] = acc[mt][nt][j] + bv;
            } else if (!isV) {
                #pragma unroll
                for (int j = 0; j < 4; ++j)
                    ((__bf16*)C0)[(size_t)(rowb + j) * 2048 + col] =
                        (__bf16)(acc[mt][nt][j] + bv);
            } else {
                const int hh = (col - 2048) >> 6, dd = (col - 2048) & 63;
                const int bb = rowb >> 11, tt = rowb & 2047;
                __bf16 p4[4];
                #pragma unroll
                for (int j = 0; j < 4; ++j) p4[j] = (__bf16)(acc[mt][nt][j] + bv);
                *(bf16x4*)&vT[((size_t)((bb * NH + hh) * HD + dd)) * T_SEQ + tt]
                    = *(const bf16x4*)p4;
            }
        }
    }
}

// ---------------------------------------------------------------------------
// MFMA flash attention, KVBLK=64, reg-staged prefetch, 2 barriers/tile.
// Block = 4 waves = (b, h, 64-row q-tile); wave owns 16 q-rows.
// qkb: [b*T+t][2048] bf16 (q|k).  vT: [b][h][d][t] bf16.  aout: [t][1024].
// ---------------------------------------------------------------------------
__global__ __launch_bounds__(256) void attn_mfma(
    const __bf16* __restrict__ qkb, const __bf16* __restrict__ vT,
    __bf16* __restrict__ aout)
{
    int bix = blockIdx.x;
    bix = (bix & 7) * 256 + (bix >> 3);     // XCD swizzle: cluster same (b,h)
    const int qt   = bix & 31;
    const int h    = (bix >> 5) & 15;
    const int b    = bix >> 9;
    const int tid  = threadIdx.x;
    const int wid  = tid >> 6;
    const int lane = tid & 63;
    const int g    = lane >> 4;
    const int n    = lane & 15;

    const int q0    = qt * 64;
    const int qbase = q0 + wid * 16;
    const int nkt   = qt + 1;

    __shared__ __bf16 Ks[64][72];           // [kv][dim], 144B rows (9x16B)
    __shared__ __bf16 Vs[64][72];           // [dim][kv]
    __shared__ __bf16 Ps[4][16][72];        // per-wave [qrow][kv]

    // Q fragments, scale 1/8 folded in (exact in bf16)
    bf16x8 qa[2];
    {
        const size_t qrow = (size_t)(b * T_SEQ + qbase + n) * 2048 + (size_t)h * HD;
        qa[0] = *(const bf16x8*)&qkb[qrow + g * 8];
        qa[1] = *(const bf16x8*)&qkb[qrow + 32 + g * 8];
        #pragma unroll
        for (int j = 0; j < 8; ++j) {
            qa[0][j] = (__bf16)((float)qa[0][j] * 0.125f);
            qa[1][j] = (__bf16)((float)qa[1][j] * 0.125f);
        }
    }

    f32x4 o[4] = {};
    float mrow[4] = {-INFINITY, -INFINITY, -INFINITY, -INFINITY};
    float lrow[4] = {0.f, 0.f, 0.f, 0.f};

    // staging: thread -> (row srow 0..63, chunks sch and sch+4 of 8 bf16)
    const int srow = tid >> 2;
    const int sch  = tid & 3;
    const __bf16* gK = qkb + (size_t)(b * T_SEQ + srow) * 2048 + 1024
                       + (size_t)h * HD + sch * 8;
    const __bf16* gV = vT + ((size_t)((b * NH + h) * HD + srow)) * T_SEQ + sch * 8;

    bf16x8 kreg0 = *(const bf16x8*)gK;
    bf16x8 kreg1 = *(const bf16x8*)(gK + 32);
    bf16x8 vreg0 = *(const bf16x8*)gV;
    bf16x8 vreg1 = *(const bf16x8*)(gV + 32);

    for (int kt = 0; kt < nkt; ++kt) {
        // write staged regs to LDS
        *(bf16x8*)&Ks[srow][sch * 8]      = kreg0;
        *(bf16x8*)&Ks[srow][sch * 8 + 32] = kreg1;
        *(bf16x8*)&Vs[srow][sch * 8]      = vreg0;
        *(bf16x8*)&Vs[srow][sch * 8 + 32] = vreg1;
        __syncthreads();

        // prefetch next tile (overlaps compute below)
        if (kt + 1 < nkt) {
            const int kb2 = (kt + 1) * 64;
            kreg0 = *(const bf16x8*)(gK + (size_t)kb2 * 2048);
            kreg1 = *(const bf16x8*)(gK + (size_t)kb2 * 2048 + 32);
            vreg0 = *(const bf16x8*)(gV + kb2);
            vreg1 = *(const bf16x8*)(gV + kb2 + 32);
        }

        // ---- S = Q K^T : 4 col-subtiles x 2 k-chunks ----
        f32x4 s4[4] = {};
        __builtin_amdgcn_s_setprio(1);
        #pragma unroll
        for (int cc = 0; cc < 2; ++cc) {
            #pragma unroll
            for (int sub = 0; sub < 4; ++sub) {
                bf16x8 kf = *(const bf16x8*)&Ks[sub * 16 + n][cc * 32 + g * 8];
                s4[sub] = __builtin_amdgcn_mfma_f32_16x16x32_bf16(
                    qa[cc], kf, s4[sub], 0, 0, 0);
            }
        }
        __builtin_amdgcn_s_setprio(0);

        // ---- online softmax ----
        const int kb0 = kt * 64;
        #pragma unroll
        for (int r = 0; r < 4; ++r) {
            const int qrow = qbase + 4 * g + r;
            float v0 = s4[0][r], v1 = s4[1][r], v2 = s4[2][r], v3 = s4[3][r];
            if (kb0 + n > qrow)      v0 = -INFINITY;
            if (kb0 + 16 + n > qrow) v1 = -INFINITY;
            if (kb0 + 32 + n > qrow) v2 = -INFINITY;
            if (kb0 + 48 + n > qrow) v3 = -INFINITY;

            float tm = fmaxf(fmaxf(v0, v1), fmaxf(v2, v3));
            #pragma unroll
            for (int off = 1; off < 16; off <<= 1)
                tm = fmaxf(tm, __shfl_xor(tm, off));

            const float mnew = fmaxf(mrow[r], tm);
            const float corr = __expf(mrow[r] - mnew);
            mrow[r] = mnew;

            const float p0 = __expf(v0 - mnew);
            const float p1 = __expf(v1 - mnew);
            const float p2 = __expf(v2 - mnew);
            const float p3 = __expf(v3 - mnew);
            float rs = (p0 + p1) + (p2 + p3);
            #pragma unroll
            for (int off = 1; off < 16; off <<= 1)
                rs += __shfl_xor(rs, off);

            lrow[r] = lrow[r] * corr + rs;
            o[0][r] *= corr; o[1][r] *= corr; o[2][r] *= corr; o[3][r] *= corr;

            Ps[wid][4 * g + r][n]      = (__bf16)p0;
            Ps[wid][4 * g + r][16 + n] = (__bf16)p1;
            Ps[wid][4 * g + r][32 + n] = (__bf16)p2;
            Ps[wid][4 * g + r][48 + n] = (__bf16)p3;
        }
        // no barrier: Ps is per-wave; same-wave DS ops complete in order

        // ---- O += P V ----
        __builtin_amdgcn_s_setprio(1);
        #pragma unroll
        for (int cc = 0; cc < 2; ++cc) {
            bf16x8 pa = *(const bf16x8*)&Ps[wid][n][cc * 32 + g * 8];
            #pragma unroll
            for (int nt = 0; nt < 4; ++nt) {
                bf16x8 vf = *(const bf16x8*)&Vs[nt * 16 + n][cc * 32 + g * 8];
                o[nt] = __builtin_amdgcn_mfma_f32_16x16x32_bf16(pa, vf, o[nt], 0, 0, 0);
            }
        }
        __builtin_amdgcn_s_setprio(0);
        __syncthreads();
    }

    float inv[4];
    #pragma unroll
    for (int r = 0; r < 4; ++r) inv[r] = 1.f / lrow[r];

    const size_t obase = (size_t)(b * T_SEQ + qbase) * D_MODEL + (size_t)h * HD;
    #pragma unroll
    for (int nt = 0; nt < 4; ++nt)
        #pragma unroll
        for (int r = 0; r < 4; ++r)
            aout[obase + (size_t)(4 * g + r) * D_MODEL + nt * 16 + n]
                = (__bf16)(o[nt][r] * inv[r]);
}

// ---------------------------------------------------------------------------
extern "C" void kernel_launch(void* const* d_in, const int* in_sizes, int n_in,
                              void* d_out, int out_size, void* d_ws, size_t ws_size,
                              hipStream_t stream)
{
    const float* x      = (const float*)d_in[0];
    const float* w_qkv  = (const float*)d_in[1];
    const float* b_qkv  = (const float*)d_in[2];
    const float* w_proj = (const float*)d_in[3];
    const float* b_proj = (const float*)d_in[4];
    float* out = (float*)d_out;

    // workspace layout (bf16)
    char* ws = (char*)d_ws;
    __bf16* qkb    = (__bf16*)ws;                                   // 8192 x 2048
    __bf16* vTb    = qkb + (size_t)M_ROWS * 2048;                   // 64 x 64 x 2048
    __bf16* xb     = vTb + (size_t)NH * B_SZ * HD * T_SEQ;          // 8192 x 1024
    __bf16* wqkvT  = xb + (size_t)M_ROWS * D_MODEL;                 // 3072 x 1024
    __bf16* wprojT = wqkvT + (size_t)N_QKV * D_MODEL;               // 1024 x 1024
    __bf16* aout   = wprojT + (size_t)D_MODEL * D_MODEL;            // 8192 x 1024

    // 1. convert x
    cvt_bf16<<<dim3(M_ROWS * D_MODEL / 8 / 256), 256, 0, stream>>>(
        x, xb, M_ROWS * D_MODEL / 8);
    // 2. transpose-convert weights -> [N][K]
    transpose_cvt<<<dim3(N_QKV / 32, D_MODEL / 32), 256, 0, stream>>>(
        w_qkv, wqkvT, D_MODEL, N_QKV);
    transpose_cvt<<<dim3(D_MODEL / 32, D_MODEL / 32), 256, 0, stream>>>(
        w_proj, wprojT, D_MODEL, D_MODEL);

    // 3. QKV projection: Q|K -> qkb, V -> vT (transposed)
    gemm_mfma<1><<<dim3((M_ROWS / 128) * (N_QKV / 128)), 256, 0, stream>>>(
        xb, wqkvT, b_qkv, qkb, vTb, M_ROWS, N_QKV, D_MODEL);

    // 4. flash attention
    attn_mfma<<<dim3(B_SZ * NH * (T_SEQ / 64)), 256, 0, stream>>>(qkb, vTb, aout);

    // 5. output projection (f32 out)
    gemm_mfma<0><<<dim3((M_ROWS / 128) * (D_MODEL / 128)), 256, 0, stream>>>(
        aout, wprojT, b_proj, out, nullptr, M_ROWS, D_MODEL, D_MODEL);
}

// Round 5
// 266.670 us; speedup vs baseline: 29.4569x; 1.0320x over previous
//
#include <hip/hip_runtime.h>
#include <hip/hip_bf16.h>
#include <math.h>

#define D_MODEL 1024
#define NH      16
#define HD      64
#define T_SEQ   2048
#define B_SZ    4
#define M_ROWS  (B_SZ * T_SEQ)       // 8192
#define N_QKV   (3 * D_MODEL)        // 3072

typedef __bf16 bf16x8 __attribute__((ext_vector_type(8)));
typedef __bf16 bf16x4 __attribute__((ext_vector_type(4)));
typedef float  f32x4  __attribute__((ext_vector_type(4)));

__device__ __forceinline__ bf16x8 cvt8(float4 a, float4 b) {
    bf16x8 v;
    v[0]=(__bf16)a.x; v[1]=(__bf16)a.y; v[2]=(__bf16)a.z; v[3]=(__bf16)a.w;
    v[4]=(__bf16)b.x; v[5]=(__bf16)b.y; v[6]=(__bf16)b.z; v[7]=(__bf16)b.w;
    return v;
}

__device__ __forceinline__ void gload_lds16(const __bf16* g, __bf16* l) {
    __builtin_amdgcn_global_load_lds(
        (const __attribute__((address_space(1))) void*)g,
        (__attribute__((address_space(3))) void*)l, 16, 0, 0);
}

// ---------------------------------------------------------------------------
// fp32 -> bf16 elementwise convert
// ---------------------------------------------------------------------------
__global__ __launch_bounds__(256) void cvt_bf16(const float* __restrict__ in,
                                                __bf16* __restrict__ out, int n8)
{
    int i = blockIdx.x * 256 + threadIdx.x;
    if (i < n8) {
        float4 a = ((const float4*)in)[2 * i];
        float4 b = ((const float4*)in)[2 * i + 1];
        ((bf16x8*)out)[i] = cvt8(a, b);
    }
}

// ---------------------------------------------------------------------------
// Transpose + convert: W[R][C] fp32 -> WT[C][R] bf16
// ---------------------------------------------------------------------------
__global__ __launch_bounds__(256) void transpose_cvt(
    const float* __restrict__ W, __bf16* __restrict__ WT, int R, int C)
{
    __shared__ float t[32][33];
    const int tr0 = blockIdx.y * 32, tc0 = blockIdx.x * 32;
    const int lr = threadIdx.x >> 5, lc = threadIdx.x & 31;
    #pragma unroll
    for (int i = 0; i < 4; ++i)
        t[lr + i * 8][lc] = W[(size_t)(tr0 + lr + i * 8) * C + tc0 + lc];
    __syncthreads();
    #pragma unroll
    for (int i = 0; i < 4; ++i)
        WT[(size_t)(tc0 + lr + i * 8) * R + tr0 + lc] = (__bf16)t[lc][lr + i * 8];
}

// ---------------------------------------------------------------------------
// bf16 MFMA GEMM (m97 structure, unchanged from R4)
// ---------------------------------------------------------------------------
template<int MODE>
__global__ __launch_bounds__(256) void gemm_mfma(
    const __bf16* __restrict__ A, const __bf16* __restrict__ BT,
    const float* __restrict__ bias, void* __restrict__ C0,
    __bf16* __restrict__ vT, int M, int N, int K)
{
    __shared__ __bf16 As[128 * 32];
    __shared__ __bf16 Bs[128 * 32];

    const int nbn = N >> 7;
    const int nwg = gridDim.x;
    int bid = blockIdx.x;
    bid = (bid & 7) * (nwg >> 3) + (bid >> 3);
    const int tm = bid / nbn, tn = bid % nbn;
    const int row0 = tm << 7, col0 = tn << 7;

    const int tid  = threadIdx.x;
    const int wid  = tid >> 6, lane = tid & 63;
    const int wm   = wid >> 1, wn = wid & 1;
    const int g    = lane >> 4, r16 = lane & 15;

    const int srow = lane >> 2;
    const int skk  = (lane & 3) * 8;

    f32x4 acc[4][4] = {};

    for (int k0 = 0; k0 < K; k0 += 32) {
        #pragma unroll
        for (int i = 0; i < 2; ++i) {
            const int seg = wid * 2 + i;
            const int row = seg * 16 + srow;
            gload_lds16(A  + (size_t)(row0 + row) * K + k0 + skk, As + seg * 512);
            gload_lds16(BT + (size_t)(col0 + row) * K + k0 + skk, Bs + seg * 512);
        }
        __syncthreads();

        bf16x8 af[4], bfr[4];
        #pragma unroll
        for (int mt = 0; mt < 4; ++mt)
            af[mt] = *(const bf16x8*)&As[(wm * 64 + mt * 16 + r16) * 32 + g * 8];
        #pragma unroll
        for (int nt = 0; nt < 4; ++nt)
            bfr[nt] = *(const bf16x8*)&Bs[(wn * 64 + nt * 16 + r16) * 32 + g * 8];
        #pragma unroll
        for (int mt = 0; mt < 4; ++mt)
            #pragma unroll
            for (int nt = 0; nt < 4; ++nt)
                acc[mt][nt] = __builtin_amdgcn_mfma_f32_16x16x32_bf16(
                    af[mt], bfr[nt], acc[mt][nt], 0, 0, 0);
        __syncthreads();
    }

    const bool isV = (MODE == 1) && (tn >= 16);

    #pragma unroll
    for (int mt = 0; mt < 4; ++mt) {
        #pragma unroll
        for (int nt = 0; nt < 4; ++nt) {
            const int col = col0 + wn * 64 + nt * 16 + r16;
            const float bv = bias[col];
            const int rowb = row0 + wm * 64 + mt * 16 + g * 4;
            if (MODE == 0) {
                #pragma unroll
                for (int j = 0; j < 4; ++j)
                    ((float*)C0)[(size_t)(rowb + j) * N + col] = acc[mt][nt][j] + bv;
            } else if (!isV) {
                #pragma unroll
                for (int j = 0; j < 4; ++j)
                    ((__bf16*)C0)[(size_t)(rowb + j) * 2048 + col] =
                        (__bf16)(acc[mt][nt][j] + bv);
            } else {
                const int hh = (col - 2048) >> 6, dd = (col - 2048) & 63;
                const int bb = rowb >> 11, tt = rowb & 2047;
                __bf16 p4[4];
                #pragma unroll
                for (int j = 0; j < 4; ++j) p4[j] = (__bf16)(acc[mt][nt][j] + bv);
                *(bf16x4*)&vT[((size_t)((bb * NH + hh) * HD + dd)) * T_SEQ + tt]
                    = *(const bf16x4*)p4;
            }
        }
    }
}

// ---------------------------------------------------------------------------
// MFMA flash attention v2.
// Block = 4 waves; processes TWO 128-row q-strips (qp and 15-qp) -> uniform
// 36 k-tiles/block, 512 blocks. Wave owns 32 q-rows (2 row-blocks of 16).
// K/V/P LDS: [row][64] bf16 linear 128B rows, XOR swizzle byte^=((row&7)<<4)
// on both sides -> conflict-free b128 reads (8 lanes per 16B slot = minimum).
// Defer-max online softmax (T13, THR=8).
// ---------------------------------------------------------------------------
__global__ __launch_bounds__(256) void attn_mfma(
    const __bf16* __restrict__ qkb, const __bf16* __restrict__ vT,
    __bf16* __restrict__ aout)
{
    int bix = blockIdx.x;
    bix = (bix & 7) * 64 + (bix >> 3);      // XCD swizzle (512 = 8*64)
    const int qp  = bix & 7;
    const int h   = (bix >> 3) & 15;
    const int b   = bix >> 7;
    const int tid  = threadIdx.x;
    const int wid  = tid >> 6;
    const int lane = tid & 63;
    const int g    = lane >> 4;
    const int n    = lane & 15;
    const int swzn = (n & 7) << 4;

    __shared__ __align__(16) char Ks[64 * 128];        // [kv][d]
    __shared__ __align__(16) char Vs[64 * 128];        // [d][kv]
    __shared__ __align__(16) char Ps[4][32 * 128];     // per-wave [q][kv]

    // staging geometry
    const int srow = tid >> 2;              // 0..63
    const int sb0  = (tid & 3) << 4;        // byte slot 0,16,32,48
    const int swzw = (srow & 7) << 4;
    const int sd8  = (tid & 3) * 8;         // element offset 0,8,16,24

    for (int pass = 0; pass < 2; ++pass) {
        const int qt    = pass ? (15 - qp) : qp;
        const int q0    = qt * 128;
        const int qbase = q0 + wid * 32;
        const int nkt   = 2 * qt + 2;

        // ---- Q fragments (scale 1/8 folded in) ----
        bf16x8 qa[2][2];
        #pragma unroll
        for (int rb = 0; rb < 2; ++rb) {
            const size_t qrow = (size_t)(b * T_SEQ + qbase + rb * 16 + n) * 2048
                                + (size_t)h * HD;
            qa[rb][0] = *(const bf16x8*)&qkb[qrow + g * 8];
            qa[rb][1] = *(const bf16x8*)&qkb[qrow + 32 + g * 8];
            #pragma unroll
            for (int j = 0; j < 8; ++j) {
                qa[rb][0][j] = (__bf16)((float)qa[rb][0][j] * 0.125f);
                qa[rb][1][j] = (__bf16)((float)qa[rb][1][j] * 0.125f);
            }
        }

        f32x4 o[2][4] = {};
        float mrow[2][4] = {};              // defer-max base m=0
        float lrow[2][4] = {};

        const __bf16* gK = qkb + (size_t)(b * T_SEQ + srow) * 2048 + 1024
                           + (size_t)h * HD + sd8;
        const __bf16* gV = vT + ((size_t)((b * NH + h) * HD + srow)) * T_SEQ + sd8;

        bf16x8 kreg0 = *(const bf16x8*)gK;
        bf16x8 kreg1 = *(const bf16x8*)(gK + 32);
        bf16x8 vreg0 = *(const bf16x8*)gV;
        bf16x8 vreg1 = *(const bf16x8*)(gV + 32);

        for (int kt = 0; kt < nkt; ++kt) {
            // ---- write staged regs to LDS (swizzled) ----
            *(bf16x8*)(Ks + srow * 128 + (sb0 ^ swzw))        = kreg0;
            *(bf16x8*)(Ks + srow * 128 + ((sb0 + 64) ^ swzw)) = kreg1;
            *(bf16x8*)(Vs + srow * 128 + (sb0 ^ swzw))        = vreg0;
            *(bf16x8*)(Vs + srow * 128 + ((sb0 + 64) ^ swzw)) = vreg1;
            __syncthreads();

            // ---- prefetch next tile ----
            if (kt + 1 < nkt) {
                const size_t kb2 = (size_t)(kt + 1) * 64;
                kreg0 = *(const bf16x8*)(gK + kb2 * 2048);
                kreg1 = *(const bf16x8*)(gK + kb2 * 2048 + 32);
                vreg0 = *(const bf16x8*)(gV + kb2);
                vreg1 = *(const bf16x8*)(gV + kb2 + 32);
            }

            // ---- S = Q K^T ----
            f32x4 s4[2][4] = {};
            __builtin_amdgcn_s_setprio(1);
            #pragma unroll
            for (int cc = 0; cc < 2; ++cc) {
                bf16x8 kf[4];
                #pragma unroll
                for (int sub = 0; sub < 4; ++sub)
                    kf[sub] = *(const bf16x8*)(Ks + (sub * 16 + n) * 128
                                               + ((cc * 64 + g * 16) ^ swzn));
                #pragma unroll
                for (int rb = 0; rb < 2; ++rb)
                    #pragma unroll
                    for (int sub = 0; sub < 4; ++sub)
                        s4[rb][sub] = __builtin_amdgcn_mfma_f32_16x16x32_bf16(
                            qa[rb][cc], kf[sub], s4[rb][sub], 0, 0, 0);
            }
            __builtin_amdgcn_s_setprio(0);

            // ---- online softmax with defer-max ----
            const int kb0 = kt * 64;
            #pragma unroll
            for (int rb = 0; rb < 2; ++rb) {
                // causal mask
                #pragma unroll
                for (int r = 0; r < 4; ++r) {
                    const int qrow = qbase + rb * 16 + 4 * g + r;
                    #pragma unroll
                    for (int sub = 0; sub < 4; ++sub)
                        if (kb0 + sub * 16 + n > qrow) s4[rb][sub][r] = -INFINITY;
                }
                // lane-local tile max per row
                float pm[4];
                int ok = 1;
                #pragma unroll
                for (int r = 0; r < 4; ++r) {
                    pm[r] = fmaxf(fmaxf(s4[rb][0][r], s4[rb][1][r]),
                                  fmaxf(s4[rb][2][r], s4[rb][3][r]));
                    ok &= (pm[r] <= mrow[rb][r] + 8.f);
                }
                if (__all(ok)) {
                    // fast path: no max-reduce, no rescale
                    #pragma unroll
                    for (int r = 0; r < 4; ++r) {
                        const float m = mrow[rb][r];
                        const float p0 = __expf(s4[rb][0][r] - m);
                        const float p1 = __expf(s4[rb][1][r] - m);
                        const float p2 = __expf(s4[rb][2][r] - m);
                        const float p3 = __expf(s4[rb][3][r] - m);
                        float rs = (p0 + p1) + (p2 + p3);
                        #pragma unroll
                        for (int off = 1; off < 16; off <<= 1)
                            rs += __shfl_xor(rs, off);
                        lrow[rb][r] += rs;
                        char* prow = Ps[wid] + (rb * 16 + 4 * g + r) * 128;
                        const int pswz = ((4 * g + r) & 7) << 4;
                        *(__bf16*)(prow + ((2 * n)      ^ pswz)) = (__bf16)p0;
                        *(__bf16*)(prow + ((2 * n + 32) ^ pswz)) = (__bf16)p1;
                        *(__bf16*)(prow + ((2 * n + 64) ^ pswz)) = (__bf16)p2;
                        *(__bf16*)(prow + ((2 * n + 96) ^ pswz)) = (__bf16)p3;
                    }
                } else {
                    // slow path: full online-softmax rescale
                    #pragma unroll
                    for (int r = 0; r < 4; ++r) {
                        float tm = pm[r];
                        #pragma unroll
                        for (int off = 1; off < 16; off <<= 1)
                            tm = fmaxf(tm, __shfl_xor(tm, off));
                        const float mnew = fmaxf(mrow[rb][r], tm);
                        const float corr = __expf(mrow[rb][r] - mnew);
                        mrow[rb][r] = mnew;
                        const float p0 = __expf(s4[rb][0][r] - mnew);
                        const float p1 = __expf(s4[rb][1][r] - mnew);
                        const float p2 = __expf(s4[rb][2][r] - mnew);
                        const float p3 = __expf(s4[rb][3][r] - mnew);
                        float rs = (p0 + p1) + (p2 + p3);
                        #pragma unroll
                        for (int off = 1; off < 16; off <<= 1)
                            rs += __shfl_xor(rs, off);
                        lrow[rb][r] = lrow[rb][r] * corr + rs;
                        #pragma unroll
                        for (int nt = 0; nt < 4; ++nt) o[rb][nt][r] *= corr;
                        char* prow = Ps[wid] + (rb * 16 + 4 * g + r) * 128;
                        const int pswz = ((4 * g + r) & 7) << 4;
                        *(__bf16*)(prow + ((2 * n)      ^ pswz)) = (__bf16)p0;
                        *(__bf16*)(prow + ((2 * n + 32) ^ pswz)) = (__bf16)p1;
                        *(__bf16*)(prow + ((2 * n + 64) ^ pswz)) = (__bf16)p2;
                        *(__bf16*)(prow + ((2 * n + 96) ^ pswz)) = (__bf16)p3;
                    }
                }
            }

            // ---- O += P V ----
            __builtin_amdgcn_s_setprio(1);
            #pragma unroll
            for (int cc = 0; cc < 2; ++cc) {
                bf16x8 vf[4];
                #pragma unroll
                for (int nt = 0; nt < 4; ++nt)
                    vf[nt] = *(const bf16x8*)(Vs + (nt * 16 + n) * 128
                                              + ((cc * 64 + g * 16) ^ swzn));
                #pragma unroll
                for (int rb = 0; rb < 2; ++rb) {
                    bf16x8 pa = *(const bf16x8*)(Ps[wid] + (rb * 16 + n) * 128
                                                 + ((cc * 64 + g * 16) ^ swzn));
                    #pragma unroll
                    for (int nt = 0; nt < 4; ++nt)
                        o[rb][nt] = __builtin_amdgcn_mfma_f32_16x16x32_bf16(
                            pa, vf[nt], o[rb][nt], 0, 0, 0);
                }
            }
            __builtin_amdgcn_s_setprio(0);
            __syncthreads();
        }

        // ---- normalize and store ----
        #pragma unroll
        for (int rb = 0; rb < 2; ++rb) {
            float inv[4];
            #pragma unroll
            for (int r = 0; r < 4; ++r) inv[r] = 1.f / lrow[rb][r];
            const size_t obase = (size_t)(b * T_SEQ + qbase + rb * 16) * D_MODEL
                                 + (size_t)h * HD;
            #pragma unroll
            for (int nt = 0; nt < 4; ++nt)
                #pragma unroll
                for (int r = 0; r < 4; ++r)
                    aout[obase + (size_t)(4 * g + r) * D_MODEL + nt * 16 + n]
                        = (__bf16)(o[rb][nt][r] * inv[r]);
        }
    }
}

// ---------------------------------------------------------------------------
extern "C" void kernel_launch(void* const* d_in, const int* in_sizes, int n_in,
                              void* d_out, int out_size, void* d_ws, size_t ws_size,
                              hipStream_t stream)
{
    const float* x      = (const float*)d_in[0];
    const float* w_qkv  = (const float*)d_in[1];
    const float* b_qkv  = (const float*)d_in[2];
    const float* w_proj = (const float*)d_in[3];
    const float* b_proj = (const float*)d_in[4];
    float* out = (float*)d_out;

    char* ws = (char*)d_ws;
    __bf16* qkb    = (__bf16*)ws;                                   // 8192 x 2048
    __bf16* vTb    = qkb + (size_t)M_ROWS * 2048;                   // 64 x 64 x 2048
    __bf16* xb     = vTb + (size_t)NH * B_SZ * HD * T_SEQ;          // 8192 x 1024
    __bf16* wqkvT  = xb + (size_t)M_ROWS * D_MODEL;                 // 3072 x 1024
    __bf16* wprojT = wqkvT + (size_t)N_QKV * D_MODEL;               // 1024 x 1024
    __bf16* aout   = wprojT + (size_t)D_MODEL * D_MODEL;            // 8192 x 1024

    cvt_bf16<<<dim3(M_ROWS * D_MODEL / 8 / 256), 256, 0, stream>>>(
        x, xb, M_ROWS * D_MODEL / 8);
    transpose_cvt<<<dim3(N_QKV / 32, D_MODEL / 32), 256, 0, stream>>>(
        w_qkv, wqkvT, D_MODEL, N_QKV);
    transpose_cvt<<<dim3(D_MODEL / 32, D_MODEL / 32), 256, 0, stream>>>(
        w_proj, wprojT, D_MODEL, D_MODEL);

    gemm_mfma<1><<<dim3((M_ROWS / 128) * (N_QKV / 128)), 256, 0, stream>>>(
        xb, wqkvT, b_qkv, qkb, vTb, M_ROWS, N_QKV, D_MODEL);

    attn_mfma<<<dim3(B_SZ * NH * (T_SEQ / 256)), 256, 0, stream>>>(qkb, vTb, aout);

    gemm_mfma<0><<<dim3((M_ROWS / 128) * (D_MODEL / 128)), 256, 0, stream>>>(
        aout, wprojT, b_proj, out, nullptr, M_ROWS, D_MODEL, D_MODEL);
}

// Round 6
// 209.539 us; speedup vs baseline: 37.4882x; 1.2726x over previous
//
#include <hip/hip_runtime.h>
#include <hip/hip_bf16.h>
#include <math.h>

#define D_MODEL 1024
#define NH      16
#define HD      64
#define T_SEQ   2048
#define B_SZ    4
#define M_ROWS  (B_SZ * T_SEQ)       // 8192
#define N_QKV   (3 * D_MODEL)        // 3072

typedef __bf16 bf16x8 __attribute__((ext_vector_type(8)));
typedef __bf16 bf16x4 __attribute__((ext_vector_type(4)));
typedef float  f32x4  __attribute__((ext_vector_type(4)));

__device__ __forceinline__ bf16x8 cvt8(float4 a, float4 b) {
    bf16x8 v;
    v[0]=(__bf16)a.x; v[1]=(__bf16)a.y; v[2]=(__bf16)a.z; v[3]=(__bf16)a.w;
    v[4]=(__bf16)b.x; v[5]=(__bf16)b.y; v[6]=(__bf16)b.z; v[7]=(__bf16)b.w;
    return v;
}

__device__ __forceinline__ void gload_lds16(const __bf16* g, __bf16* l) {
    __builtin_amdgcn_global_load_lds(
        (const __attribute__((address_space(1))) void*)g,
        (__attribute__((address_space(3))) void*)l, 16, 0, 0);
}

// ---------------------------------------------------------------------------
// fp32 -> bf16 elementwise convert
// ---------------------------------------------------------------------------
__global__ __launch_bounds__(256) void cvt_bf16(const float* __restrict__ in,
                                                __bf16* __restrict__ out, int n8)
{
    int i = blockIdx.x * 256 + threadIdx.x;
    if (i < n8) {
        float4 a = ((const float4*)in)[2 * i];
        float4 b = ((const float4*)in)[2 * i + 1];
        ((bf16x8*)out)[i] = cvt8(a, b);
    }
}

// ---------------------------------------------------------------------------
// Transpose + convert: W[R][C] fp32 -> WT[C][R] bf16
// ---------------------------------------------------------------------------
__global__ __launch_bounds__(256) void transpose_cvt(
    const float* __restrict__ W, __bf16* __restrict__ WT, int R, int C)
{
    __shared__ float t[32][33];
    const int tr0 = blockIdx.y * 32, tc0 = blockIdx.x * 32;
    const int lr = threadIdx.x >> 5, lc = threadIdx.x & 31;
    #pragma unroll
    for (int i = 0; i < 4; ++i)
        t[lr + i * 8][lc] = W[(size_t)(tr0 + lr + i * 8) * C + tc0 + lc];
    __syncthreads();
    #pragma unroll
    for (int i = 0; i < 4; ++i)
        WT[(size_t)(tc0 + lr + i * 8) * R + tr0 + lc] = (__bf16)t[lc][lr + i * 8];
}

// ---------------------------------------------------------------------------
// bf16 MFMA GEMM (m97 structure, unchanged)
// ---------------------------------------------------------------------------
template<int MODE>
__global__ __launch_bounds__(256) void gemm_mfma(
    const __bf16* __restrict__ A, const __bf16* __restrict__ BT,
    const float* __restrict__ bias, void* __restrict__ C0,
    __bf16* __restrict__ vT, int M, int N, int K)
{
    __shared__ __bf16 As[128 * 32];
    __shared__ __bf16 Bs[128 * 32];

    const int nbn = N >> 7;
    const int nwg = gridDim.x;
    int bid = blockIdx.x;
    bid = (bid & 7) * (nwg >> 3) + (bid >> 3);
    const int tm = bid / nbn, tn = bid % nbn;
    const int row0 = tm << 7, col0 = tn << 7;

    const int tid  = threadIdx.x;
    const int wid  = tid >> 6, lane = tid & 63;
    const int wm   = wid >> 1, wn = wid & 1;
    const int g    = lane >> 4, r16 = lane & 15;

    const int srow = lane >> 2;
    const int skk  = (lane & 3) * 8;

    f32x4 acc[4][4] = {};

    for (int k0 = 0; k0 < K; k0 += 32) {
        #pragma unroll
        for (int i = 0; i < 2; ++i) {
            const int seg = wid * 2 + i;
            const int row = seg * 16 + srow;
            gload_lds16(A  + (size_t)(row0 + row) * K + k0 + skk, As + seg * 512);
            gload_lds16(BT + (size_t)(col0 + row) * K + k0 + skk, Bs + seg * 512);
        }
        __syncthreads();

        bf16x8 af[4], bfr[4];
        #pragma unroll
        for (int mt = 0; mt < 4; ++mt)
            af[mt] = *(const bf16x8*)&As[(wm * 64 + mt * 16 + r16) * 32 + g * 8];
        #pragma unroll
        for (int nt = 0; nt < 4; ++nt)
            bfr[nt] = *(const bf16x8*)&Bs[(wn * 64 + nt * 16 + r16) * 32 + g * 8];
        #pragma unroll
        for (int mt = 0; mt < 4; ++mt)
            #pragma unroll
            for (int nt = 0; nt < 4; ++nt)
                acc[mt][nt] = __builtin_amdgcn_mfma_f32_16x16x32_bf16(
                    af[mt], bfr[nt], acc[mt][nt], 0, 0, 0);
        __syncthreads();
    }

    const bool isV = (MODE == 1) && (tn >= 16);

    #pragma unroll
    for (int mt = 0; mt < 4; ++mt) {
        #pragma unroll
        for (int nt = 0; nt < 4; ++nt) {
            const int col = col0 + wn * 64 + nt * 16 + r16;
            const float bv = bias[col];
            const int rowb = row0 + wm * 64 + mt * 16 + g * 4;
            if (MODE == 0) {
                #pragma unroll
                for (int j = 0; j < 4; ++j)
                    ((float*)C0)[(size_t)(rowb + j) * N + col] = acc[mt][nt][j] + bv;
            } else if (!isV) {
                #pragma unroll
                for (int j = 0; j < 4; ++j)
                    ((__bf16*)C0)[(size_t)(rowb + j) * 2048 + col] =
                        (__bf16)(acc[mt][nt][j] + bv);
            } else {
                const int hh = (col - 2048) >> 6, dd = (col - 2048) & 63;
                const int bb = rowb >> 11, tt = rowb & 2047;
                __bf16 p4[4];
                #pragma unroll
                for (int j = 0; j < 4; ++j) p4[j] = (__bf16)(acc[mt][nt][j] + bv);
                *(bf16x4*)&vT[((size_t)((bb * NH + hh) * HD + dd)) * T_SEQ + tt]
                    = *(const bf16x4*)p4;
            }
        }
    }
}

// ---------------------------------------------------------------------------
// MFMA flash attention v3.
// Block = 4 waves = one 128-row q-strip; wave owns 32 q-rows.  Grid 1024,
// heavy strips (qt=15) dispatched first for load balance; ~3 blocks/CU
// co-resident so softmax VALU of one block overlaps MFMA of another.
// Per-tile VALU diet: lane-partial lrow (one butterfly at end of block),
// wave-uniform causal-mask skip, defer-max (THR=8).
// K/V/P LDS swizzled byte^=((row&7)<<4) -> ~conflict-free b128.
// ---------------------------------------------------------------------------
__global__ __launch_bounds__(256) void attn_mfma(
    const __bf16* __restrict__ qkb, const __bf16* __restrict__ vT,
    __bf16* __restrict__ aout)
{
    const int idx = blockIdx.x;             // 0..1023
    const int qt  = 15 - (idx >> 6);        // heavy strips first
    const int bh  = idx & 63;
    const int b   = bh >> 4;
    const int h   = bh & 15;
    const int tid  = threadIdx.x;
    const int wid  = tid >> 6;
    const int lane = tid & 63;
    const int g    = lane >> 4;
    const int n    = lane & 15;
    const int swzn = (n & 7) << 4;

    const int q0    = qt * 128;
    const int qbase = q0 + wid * 32;
    const int nkt   = 2 * qt + 2;

    __shared__ __align__(16) char Ks[64 * 128];        // [kv][d]
    __shared__ __align__(16) char Vs[64 * 128];        // [d][kv]
    __shared__ __align__(16) char Ps[4][32 * 128];     // per-wave [q][kv]

    // staging geometry
    const int srow = tid >> 2;              // 0..63
    const int sb0  = (tid & 3) << 4;        // byte slot 0,16,32,48
    const int swzw = (srow & 7) << 4;
    const int sd8  = (tid & 3) * 8;

    // ---- Q fragments (scale 1/8 folded in, exact) ----
    bf16x8 qa[2][2];
    #pragma unroll
    for (int rb = 0; rb < 2; ++rb) {
        const size_t qrow = (size_t)(b * T_SEQ + qbase + rb * 16 + n) * 2048
                            + (size_t)h * HD;
        qa[rb][0] = *(const bf16x8*)&qkb[qrow + g * 8];
        qa[rb][1] = *(const bf16x8*)&qkb[qrow + 32 + g * 8];
        #pragma unroll
        for (int j = 0; j < 8; ++j) {
            qa[rb][0][j] = (__bf16)((float)qa[rb][0][j] * 0.125f);
            qa[rb][1][j] = (__bf16)((float)qa[rb][1][j] * 0.125f);
        }
    }

    f32x4 o[2][4] = {};
    float mrow[2][4] = {};                  // defer-max base m=0
    float lrow[2][4] = {};                  // LANE-PARTIAL row sums

    const __bf16* gK = qkb + (size_t)(b * T_SEQ + srow) * 2048 + 1024
                       + (size_t)h * HD + sd8;
    const __bf16* gV = vT + ((size_t)((b * NH + h) * HD + srow)) * T_SEQ + sd8;

    bf16x8 kreg0 = *(const bf16x8*)gK;
    bf16x8 kreg1 = *(const bf16x8*)(gK + 32);
    bf16x8 vreg0 = *(const bf16x8*)gV;
    bf16x8 vreg1 = *(const bf16x8*)(gV + 32);

    for (int kt = 0; kt < nkt; ++kt) {
        *(bf16x8*)(Ks + srow * 128 + (sb0 ^ swzw))        = kreg0;
        *(bf16x8*)(Ks + srow * 128 + ((sb0 + 64) ^ swzw)) = kreg1;
        *(bf16x8*)(Vs + srow * 128 + (sb0 ^ swzw))        = vreg0;
        *(bf16x8*)(Vs + srow * 128 + ((sb0 + 64) ^ swzw)) = vreg1;
        __syncthreads();

        if (kt + 1 < nkt) {
            const size_t kb2 = (size_t)(kt + 1) * 64;
            kreg0 = *(const bf16x8*)(gK + kb2 * 2048);
            kreg1 = *(const bf16x8*)(gK + kb2 * 2048 + 32);
            vreg0 = *(const bf16x8*)(gV + kb2);
            vreg1 = *(const bf16x8*)(gV + kb2 + 32);
        }

        // ---- S = Q K^T ----
        f32x4 s4[2][4] = {};
        __builtin_amdgcn_s_setprio(1);
        #pragma unroll
        for (int cc = 0; cc < 2; ++cc) {
            bf16x8 kf[4];
            #pragma unroll
            for (int sub = 0; sub < 4; ++sub)
                kf[sub] = *(const bf16x8*)(Ks + (sub * 16 + n) * 128
                                           + ((cc * 64 + g * 16) ^ swzn));
            #pragma unroll
            for (int rb = 0; rb < 2; ++rb)
                #pragma unroll
                for (int sub = 0; sub < 4; ++sub)
                    s4[rb][sub] = __builtin_amdgcn_mfma_f32_16x16x32_bf16(
                        qa[rb][cc], kf[sub], s4[rb][sub], 0, 0, 0);
        }
        __builtin_amdgcn_s_setprio(0);

        const int kb0 = kt * 64;
        const bool needmask = (kb0 + 63 > qbase);   // wave-uniform

        #pragma unroll
        for (int rb = 0; rb < 2; ++rb) {
            if (needmask) {
                #pragma unroll
                for (int r = 0; r < 4; ++r) {
                    const int qrow = qbase + rb * 16 + 4 * g + r;
                    #pragma unroll
                    for (int sub = 0; sub < 4; ++sub)
                        if (kb0 + sub * 16 + n > qrow) s4[rb][sub][r] = -INFINITY;
                }
            }
            float pm[4];
            int ok = 1;
            #pragma unroll
            for (int r = 0; r < 4; ++r) {
                pm[r] = fmaxf(fmaxf(s4[rb][0][r], s4[rb][1][r]),
                              fmaxf(s4[rb][2][r], s4[rb][3][r]));
                ok &= (pm[r] <= mrow[rb][r] + 8.f);
            }
            if (__all(ok)) {
                // fast path: no max-reduce, no rescale, lane-partial sum
                #pragma unroll
                for (int r = 0; r < 4; ++r) {
                    const float m = mrow[rb][r];
                    const float p0 = __expf(s4[rb][0][r] - m);
                    const float p1 = __expf(s4[rb][1][r] - m);
                    const float p2 = __expf(s4[rb][2][r] - m);
                    const float p3 = __expf(s4[rb][3][r] - m);
                    lrow[rb][r] += (p0 + p1) + (p2 + p3);
                    char* prow = Ps[wid] + (rb * 16 + 4 * g + r) * 128;
                    const int pswz = ((4 * g + r) & 7) << 4;
                    *(__bf16*)(prow + ((2 * n)      ^ pswz)) = (__bf16)p0;
                    *(__bf16*)(prow + ((2 * n + 32) ^ pswz)) = (__bf16)p1;
                    *(__bf16*)(prow + ((2 * n + 64) ^ pswz)) = (__bf16)p2;
                    *(__bf16*)(prow + ((2 * n + 96) ^ pswz)) = (__bf16)p3;
                }
            } else {
                // slow path: butterfly max, rescale o and partial lrow
                #pragma unroll
                for (int r = 0; r < 4; ++r) {
                    float tm = pm[r];
                    #pragma unroll
                    for (int off = 1; off < 16; off <<= 1)
                        tm = fmaxf(tm, __shfl_xor(tm, off));
                    const float mnew = fmaxf(mrow[rb][r], tm);
                    const float corr = __expf(mrow[rb][r] - mnew);
                    mrow[rb][r] = mnew;
                    const float p0 = __expf(s4[rb][0][r] - mnew);
                    const float p1 = __expf(s4[rb][1][r] - mnew);
                    const float p2 = __expf(s4[rb][2][r] - mnew);
                    const float p3 = __expf(s4[rb][3][r] - mnew);
                    lrow[rb][r] = lrow[rb][r] * corr + (p0 + p1) + (p2 + p3);
                    #pragma unroll
                    for (int nt = 0; nt < 4; ++nt) o[rb][nt][r] *= corr;
                    char* prow = Ps[wid] + (rb * 16 + 4 * g + r) * 128;
                    const int pswz = ((4 * g + r) & 7) << 4;
                    *(__bf16*)(prow + ((2 * n)      ^ pswz)) = (__bf16)p0;
                    *(__bf16*)(prow + ((2 * n + 32) ^ pswz)) = (__bf16)p1;
                    *(__bf16*)(prow + ((2 * n + 64) ^ pswz)) = (__bf16)p2;
                    *(__bf16*)(prow + ((2 * n + 96) ^ pswz)) = (__bf16)p3;
                }
            }
        }

        // ---- O += P V ----
        __builtin_amdgcn_s_setprio(1);
        #pragma unroll
        for (int cc = 0; cc < 2; ++cc) {
            bf16x8 vf[4];
            #pragma unroll
            for (int nt = 0; nt < 4; ++nt)
                vf[nt] = *(const bf16x8*)(Vs + (nt * 16 + n) * 128
                                          + ((cc * 64 + g * 16) ^ swzn));
            #pragma unroll
            for (int rb = 0; rb < 2; ++rb) {
                bf16x8 pa = *(const bf16x8*)(Ps[wid] + (rb * 16 + n) * 128
                                             + ((cc * 64 + g * 16) ^ swzn));
                #pragma unroll
                for (int nt = 0; nt < 4; ++nt)
                    o[rb][nt] = __builtin_amdgcn_mfma_f32_16x16x32_bf16(
                        pa, vf[nt], o[rb][nt], 0, 0, 0);
            }
        }
        __builtin_amdgcn_s_setprio(0);
        __syncthreads();
    }

    // ---- final 16-lane reduce of lrow, normalize, store ----
    #pragma unroll
    for (int rb = 0; rb < 2; ++rb) {
        float inv[4];
        #pragma unroll
        for (int r = 0; r < 4; ++r) {
            float s = lrow[rb][r];
            #pragma unroll
            for (int off = 1; off < 16; off <<= 1)
                s += __shfl_xor(s, off);
            inv[r] = 1.f / s;
        }
        const size_t obase = (size_t)(b * T_SEQ + qbase + rb * 16) * D_MODEL
                             + (size_t)h * HD;
        #pragma unroll
        for (int nt = 0; nt < 4; ++nt)
            #pragma unroll
            for (int r = 0; r < 4; ++r)
                aout[obase + (size_t)(4 * g + r) * D_MODEL + nt * 16 + n]
                    = (__bf16)(o[rb][nt][r] * inv[r]);
    }
}

// ---------------------------------------------------------------------------
extern "C" void kernel_launch(void* const* d_in, const int* in_sizes, int n_in,
                              void* d_out, int out_size, void* d_ws, size_t ws_size,
                              hipStream_t stream)
{
    const float* x      = (const float*)d_in[0];
    const float* w_qkv  = (const float*)d_in[1];
    const float* b_qkv  = (const float*)d_in[2];
    const float* w_proj = (const float*)d_in[3];
    const float* b_proj = (const float*)d_in[4];
    float* out = (float*)d_out;

    char* ws = (char*)d_ws;
    __bf16* qkb    = (__bf16*)ws;                                   // 8192 x 2048
    __bf16* vTb    = qkb + (size_t)M_ROWS * 2048;                   // 64 x 64 x 2048
    __bf16* xb     = vTb + (size_t)NH * B_SZ * HD * T_SEQ;          // 8192 x 1024
    __bf16* wqkvT  = xb + (size_t)M_ROWS * D_MODEL;                 // 3072 x 1024
    __bf16* wprojT = wqkvT + (size_t)N_QKV * D_MODEL;               // 1024 x 1024
    __bf16* aout   = wprojT + (size_t)D_MODEL * D_MODEL;            // 8192 x 1024

    cvt_bf16<<<dim3(M_ROWS * D_MODEL / 8 / 256), 256, 0, stream>>>(
        x, xb, M_ROWS * D_MODEL / 8);
    transpose_cvt<<<dim3(N_QKV / 32, D_MODEL / 32), 256, 0, stream>>>(
        w_qkv, wqkvT, D_MODEL, N_QKV);
    transpose_cvt<<<dim3(D_MODEL / 32, D_MODEL / 32), 256, 0, stream>>>(
        w_proj, wprojT, D_MODEL, D_MODEL);

    gemm_mfma<1><<<dim3((M_ROWS / 128) * (N_QKV / 128)), 256, 0, stream>>>(
        xb, wqkvT, b_qkv, qkb, vTb, M_ROWS, N_QKV, D_MODEL);

    attn_mfma<<<dim3(B_SZ * NH * 16), 256, 0, stream>>>(qkb, vTb, aout);

    gemm_mfma<0><<<dim3((M_ROWS / 128) * (D_MODEL / 128)), 256, 0, stream>>>(
        aout, wprojT, b_proj, out, nullptr, M_ROWS, D_MODEL, D_MODEL);
}

// Round 7
// 195.356 us; speedup vs baseline: 40.2099x; 1.0726x over previous
//
#include <hip/hip_runtime.h>
#include <hip/hip_bf16.h>
#include <math.h>

#define D_MODEL 1024
#define NH      16
#define HD      64
#define T_SEQ   2048
#define B_SZ    4
#define M_ROWS  (B_SZ * T_SEQ)       // 8192
#define N_QKV   (3 * D_MODEL)        // 3072

typedef __bf16 bf16x8 __attribute__((ext_vector_type(8)));
typedef __bf16 bf16x4 __attribute__((ext_vector_type(4)));
typedef float  f32x4  __attribute__((ext_vector_type(4)));

__device__ __forceinline__ bf16x8 cvt8(float4 a, float4 b) {
    bf16x8 v;
    v[0]=(__bf16)a.x; v[1]=(__bf16)a.y; v[2]=(__bf16)a.z; v[3]=(__bf16)a.w;
    v[4]=(__bf16)b.x; v[5]=(__bf16)b.y; v[6]=(__bf16)b.z; v[7]=(__bf16)b.w;
    return v;
}

__device__ __forceinline__ void gload_lds16(const __bf16* g, __bf16* l) {
    __builtin_amdgcn_global_load_lds(
        (const __attribute__((address_space(1))) void*)g,
        (__attribute__((address_space(3))) void*)l, 16, 0, 0);
}

// raw v_exp_f32: computes 2^x (input already in log2 units)
__device__ __forceinline__ float exp2v(float x) {
    float r;
    asm("v_exp_f32 %0, %1" : "=v"(r) : "v"(x));
    return r;
}

// ---------------------------------------------------------------------------
// fp32 -> bf16 elementwise convert
// ---------------------------------------------------------------------------
__global__ __launch_bounds__(256) void cvt_bf16(const float* __restrict__ in,
                                                __bf16* __restrict__ out, int n8)
{
    int i = blockIdx.x * 256 + threadIdx.x;
    if (i < n8) {
        float4 a = ((const float4*)in)[2 * i];
        float4 b = ((const float4*)in)[2 * i + 1];
        ((bf16x8*)out)[i] = cvt8(a, b);
    }
}

// ---------------------------------------------------------------------------
// Transpose + convert: W[R][C] fp32 -> WT[C][R] bf16
// ---------------------------------------------------------------------------
__global__ __launch_bounds__(256) void transpose_cvt(
    const float* __restrict__ W, __bf16* __restrict__ WT, int R, int C)
{
    __shared__ float t[32][33];
    const int tr0 = blockIdx.y * 32, tc0 = blockIdx.x * 32;
    const int lr = threadIdx.x >> 5, lc = threadIdx.x & 31;
    #pragma unroll
    for (int i = 0; i < 4; ++i)
        t[lr + i * 8][lc] = W[(size_t)(tr0 + lr + i * 8) * C + tc0 + lc];
    __syncthreads();
    #pragma unroll
    for (int i = 0; i < 4; ++i)
        WT[(size_t)(tc0 + lr + i * 8) * R + tr0 + lc] = (__bf16)t[lc][lr + i * 8];
}

// ---------------------------------------------------------------------------
// bf16 MFMA GEMM: 128x128 tile, BK=64, 4 waves, 4x4 16x16x32 frags.
// LDS [128 rows][64 k] linear via global_load_lds; bank-conflict-free reads
// via both-sides XOR swizzle (rule #21): linear LDS dest + inverse-swizzled
// GLOBAL source (k-chunk c stored at slot c^(row&7)) + swizzled read
// (byte ^= (row&7)<<4).  16 K-steps instead of 32 -> half the barrier drains.
// MODE 0: float C (proj).  MODE 1: Q|K -> qkb bf16, V -> vT transposed.
// ---------------------------------------------------------------------------
template<int MODE>
__global__ __launch_bounds__(256) void gemm_mfma(
    const __bf16* __restrict__ A, const __bf16* __restrict__ BT,
    const float* __restrict__ bias, void* __restrict__ C0,
    __bf16* __restrict__ vT, int M, int N, int K)
{
    __shared__ __bf16 As[128 * 64];
    __shared__ __bf16 Bs[128 * 64];

    const int nbn = N >> 7;
    const int nwg = gridDim.x;
    int bid = blockIdx.x;
    bid = (bid & 7) * (nwg >> 3) + (bid >> 3);       // XCD swizzle (nwg % 8 == 0)
    const int tm = bid / nbn, tn = bid % nbn;
    const int row0 = tm << 7, col0 = tn << 7;

    const int tid  = threadIdx.x;
    const int wid  = tid >> 6, lane = tid & 63;
    const int wm   = wid >> 1, wn = wid & 1;
    const int g    = lane >> 4, r16 = lane & 15;

    f32x4 acc[4][4] = {};

    for (int k0 = 0; k0 < K; k0 += 64) {
        // stage: 16 segs of 1KB per operand (seg = 8 rows x 64 k), 4 per wave.
        // source k pre-swizzled so linear LDS holds chunk c at slot c^(row&7).
        #pragma unroll
        for (int i = 0; i < 4; ++i) {
            const int seg = wid * 4 + i;                 // 0..15
            const int row = seg * 8 + (lane >> 3);       // 0..127
            const int kel = ((lane & 7) * 8) ^ ((row & 7) * 8);
            gload_lds16(A  + (size_t)(row0 + row) * K + k0 + kel, As + seg * 512);
            gload_lds16(BT + (size_t)(col0 + row) * K + k0 + kel, Bs + seg * 512);
        }
        __syncthreads();                                 // drain loads + barrier

        #pragma unroll
        for (int kk = 0; kk < 2; ++kk) {
            bf16x8 af[4], bfr[4];
            #pragma unroll
            for (int mt = 0; mt < 4; ++mt) {
                const int row = wm * 64 + mt * 16 + r16;
                af[mt] = *(const bf16x8*)((const char*)As + row * 128
                             + ((kk * 64 + g * 16) ^ ((row & 7) << 4)));
            }
            #pragma unroll
            for (int nt = 0; nt < 4; ++nt) {
                const int row = wn * 64 + nt * 16 + r16;
                bfr[nt] = *(const bf16x8*)((const char*)Bs + row * 128
                             + ((kk * 64 + g * 16) ^ ((row & 7) << 4)));
            }
            #pragma unroll
            for (int mt = 0; mt < 4; ++mt)
                #pragma unroll
                for (int nt = 0; nt < 4; ++nt)
                    acc[mt][nt] = __builtin_amdgcn_mfma_f32_16x16x32_bf16(
                        af[mt], bfr[nt], acc[mt][nt], 0, 0, 0);
        }
        __syncthreads();                                 // reads done before next stage
    }

    const bool isV = (MODE == 1) && (tn >= 16);

    #pragma unroll
    for (int mt = 0; mt < 4; ++mt) {
        #pragma unroll
        for (int nt = 0; nt < 4; ++nt) {
            const int col = col0 + wn * 64 + nt * 16 + r16;
            const float bv = bias[col];
            const int rowb = row0 + wm * 64 + mt * 16 + g * 4;
            if (MODE == 0) {
                #pragma unroll
                for (int j = 0; j < 4; ++j)
                    ((float*)C0)[(size_t)(rowb + j) * N + col] = acc[mt][nt][j] + bv;
            } else if (!isV) {
                #pragma unroll
                for (int j = 0; j < 4; ++j)
                    ((__bf16*)C0)[(size_t)(rowb + j) * 2048 + col] =
                        (__bf16)(acc[mt][nt][j] + bv);
            } else {
                const int hh = (col - 2048) >> 6, dd = (col - 2048) & 63;
                const int bb = rowb >> 11, tt = rowb & 2047;
                __bf16 p4[4];
                #pragma unroll
                for (int j = 0; j < 4; ++j) p4[j] = (__bf16)(acc[mt][nt][j] + bv);
                *(bf16x4*)&vT[((size_t)((bb * NH + hh) * HD + dd)) * T_SEQ + tt]
                    = *(const bf16x4*)p4;
            }
        }
    }
}

// ---------------------------------------------------------------------------
// MFMA flash attention v3.1 (v3 + exp2 folding).
// Q pre-scaled by 0.125*log2(e) -> scores in log2 units -> raw v_exp_f32.
// ---------------------------------------------------------------------------
__global__ __launch_bounds__(256) void attn_mfma(
    const __bf16* __restrict__ qkb, const __bf16* __restrict__ vT,
    __bf16* __restrict__ aout)
{
    const int idx = blockIdx.x;             // 0..1023
    const int qt  = 15 - (idx >> 6);        // heavy strips first
    const int bh  = idx & 63;
    const int b   = bh >> 4;
    const int h   = bh & 15;
    const int tid  = threadIdx.x;
    const int wid  = tid >> 6;
    const int lane = tid & 63;
    const int g    = lane >> 4;
    const int n    = lane & 15;
    const int swzn = (n & 7) << 4;

    const int q0    = qt * 128;
    const int qbase = q0 + wid * 32;
    const int nkt   = 2 * qt + 2;

    __shared__ __align__(16) char Ks[64 * 128];        // [kv][d]
    __shared__ __align__(16) char Vs[64 * 128];        // [d][kv]
    __shared__ __align__(16) char Ps[4][32 * 128];     // per-wave [q][kv]

    const int srow = tid >> 2;              // 0..63
    const int sb0  = (tid & 3) << 4;        // byte slot 0,16,32,48
    const int swzw = (srow & 7) << 4;
    const int sd8  = (tid & 3) * 8;

    // ---- Q fragments: scale 1/8 * log2(e) folded in (scores -> log2 units) ----
    const float qscale = 0.125f * 1.44269504089f;
    bf16x8 qa[2][2];
    #pragma unroll
    for (int rb = 0; rb < 2; ++rb) {
        const size_t qrow = (size_t)(b * T_SEQ + qbase + rb * 16 + n) * 2048
                            + (size_t)h * HD;
        qa[rb][0] = *(const bf16x8*)&qkb[qrow + g * 8];
        qa[rb][1] = *(const bf16x8*)&qkb[qrow + 32 + g * 8];
        #pragma unroll
        for (int j = 0; j < 8; ++j) {
            qa[rb][0][j] = (__bf16)((float)qa[rb][0][j] * qscale);
            qa[rb][1][j] = (__bf16)((float)qa[rb][1][j] * qscale);
        }
    }

    f32x4 o[2][4] = {};
    float mrow[2][4] = {};                  // defer-max base m=0 (log2 units)
    float lrow[2][4] = {};                  // lane-partial row sums

    const __bf16* gK = qkb + (size_t)(b * T_SEQ + srow) * 2048 + 1024
                       + (size_t)h * HD + sd8;
    const __bf16* gV = vT + ((size_t)((b * NH + h) * HD + srow)) * T_SEQ + sd8;

    bf16x8 kreg0 = *(const bf16x8*)gK;
    bf16x8 kreg1 = *(const bf16x8*)(gK + 32);
    bf16x8 vreg0 = *(const bf16x8*)gV;
    bf16x8 vreg1 = *(const bf16x8*)(gV + 32);

    for (int kt = 0; kt < nkt; ++kt) {
        *(bf16x8*)(Ks + srow * 128 + (sb0 ^ swzw))        = kreg0;
        *(bf16x8*)(Ks + srow * 128 + ((sb0 + 64) ^ swzw)) = kreg1;
        *(bf16x8*)(Vs + srow * 128 + (sb0 ^ swzw))        = vreg0;
        *(bf16x8*)(Vs + srow * 128 + ((sb0 + 64) ^ swzw)) = vreg1;
        __syncthreads();

        if (kt + 1 < nkt) {
            const size_t kb2 = (size_t)(kt + 1) * 64;
            kreg0 = *(const bf16x8*)(gK + kb2 * 2048);
            kreg1 = *(const bf16x8*)(gK + kb2 * 2048 + 32);
            vreg0 = *(const bf16x8*)(gV + kb2);
            vreg1 = *(const bf16x8*)(gV + kb2 + 32);
        }

        // ---- S = Q K^T (log2 units) ----
        f32x4 s4[2][4] = {};
        __builtin_amdgcn_s_setprio(1);
        #pragma unroll
        for (int cc = 0; cc < 2; ++cc) {
            bf16x8 kf[4];
            #pragma unroll
            for (int sub = 0; sub < 4; ++sub)
                kf[sub] = *(const bf16x8*)(Ks + (sub * 16 + n) * 128
                                           + ((cc * 64 + g * 16) ^ swzn));
            #pragma unroll
            for (int rb = 0; rb < 2; ++rb)
                #pragma unroll
                for (int sub = 0; sub < 4; ++sub)
                    s4[rb][sub] = __builtin_amdgcn_mfma_f32_16x16x32_bf16(
                        qa[rb][cc], kf[sub], s4[rb][sub], 0, 0, 0);
        }
        __builtin_amdgcn_s_setprio(0);

        const int kb0 = kt * 64;
        const bool needmask = (kb0 + 63 > qbase);   // wave-uniform

        #pragma unroll
        for (int rb = 0; rb < 2; ++rb) {
            if (needmask) {
                #pragma unroll
                for (int r = 0; r < 4; ++r) {
                    const int qrow = qbase + rb * 16 + 4 * g + r;
                    #pragma unroll
                    for (int sub = 0; sub < 4; ++sub)
                        if (kb0 + sub * 16 + n > qrow) s4[rb][sub][r] = -INFINITY;
                }
            }
            float pm[4];
            int ok = 1;
            #pragma unroll
            for (int r = 0; r < 4; ++r) {
                pm[r] = fmaxf(fmaxf(s4[rb][0][r], s4[rb][1][r]),
                              fmaxf(s4[rb][2][r], s4[rb][3][r]));
                ok &= (pm[r] <= mrow[rb][r] + 8.f);
            }
            if (__all(ok)) {
                // fast path: no max-reduce, no rescale, lane-partial sum
                #pragma unroll
                for (int r = 0; r < 4; ++r) {
                    const float m = mrow[rb][r];
                    const float p0 = exp2v(s4[rb][0][r] - m);
                    const float p1 = exp2v(s4[rb][1][r] - m);
                    const float p2 = exp2v(s4[rb][2][r] - m);
                    const float p3 = exp2v(s4[rb][3][r] - m);
                    lrow[rb][r] += (p0 + p1) + (p2 + p3);
                    char* prow = Ps[wid] + (rb * 16 + 4 * g + r) * 128;
                    const int pswz = ((4 * g + r) & 7) << 4;
                    *(__bf16*)(prow + ((2 * n)      ^ pswz)) = (__bf16)p0;
                    *(__bf16*)(prow + ((2 * n + 32) ^ pswz)) = (__bf16)p1;
                    *(__bf16*)(prow + ((2 * n + 64) ^ pswz)) = (__bf16)p2;
                    *(__bf16*)(prow + ((2 * n + 96) ^ pswz)) = (__bf16)p3;
                }
            } else {
                // slow path: butterfly max, rescale o and partial lrow
                #pragma unroll
                for (int r = 0; r < 4; ++r) {
                    float tm = pm[r];
                    #pragma unroll
                    for (int off = 1; off < 16; off <<= 1)
                        tm = fmaxf(tm, __shfl_xor(tm, off));
                    const float mnew = fmaxf(mrow[rb][r], tm);
                    const float corr = exp2v(mrow[rb][r] - mnew);
                    mrow[rb][r] = mnew;
                    const float p0 = exp2v(s4[rb][0][r] - mnew);
                    const float p1 = exp2v(s4[rb][1][r] - mnew);
                    const float p2 = exp2v(s4[rb][2][r] - mnew);
                    const float p3 = exp2v(s4[rb][3][r] - mnew);
                    lrow[rb][r] = lrow[rb][r] * corr + (p0 + p1) + (p2 + p3);
                    #pragma unroll
                    for (int nt = 0; nt < 4; ++nt) o[rb][nt][r] *= corr;
                    char* prow = Ps[wid] + (rb * 16 + 4 * g + r) * 128;
                    const int pswz = ((4 * g + r) & 7) << 4;
                    *(__bf16*)(prow + ((2 * n)      ^ pswz)) = (__bf16)p0;
                    *(__bf16*)(prow + ((2 * n + 32) ^ pswz)) = (__bf16)p1;
                    *(__bf16*)(prow + ((2 * n + 64) ^ pswz)) = (__bf16)p2;
                    *(__bf16*)(prow + ((2 * n + 96) ^ pswz)) = (__bf16)p3;
                }
            }
        }

        // ---- O += P V ----
        __builtin_amdgcn_s_setprio(1);
        #pragma unroll
        for (int cc = 0; cc < 2; ++cc) {
            bf16x8 vf[4];
            #pragma unroll
            for (int nt = 0; nt < 4; ++nt)
                vf[nt] = *(const bf16x8*)(Vs + (nt * 16 + n) * 128
                                          + ((cc * 64 + g * 16) ^ swzn));
            #pragma unroll
            for (int rb = 0; rb < 2; ++rb) {
                bf16x8 pa = *(const bf16x8*)(Ps[wid] + (rb * 16 + n) * 128
                                             + ((cc * 64 + g * 16) ^ swzn));
                #pragma unroll
                for (int nt = 0; nt < 4; ++nt)
                    o[rb][nt] = __builtin_amdgcn_mfma_f32_16x16x32_bf16(
                        pa, vf[nt], o[rb][nt], 0, 0, 0);
            }
        }
        __builtin_amdgcn_s_setprio(0);
        __syncthreads();
    }

    // ---- final 16-lane reduce of lrow, normalize, store ----
    #pragma unroll
    for (int rb = 0; rb < 2; ++rb) {
        float inv[4];
        #pragma unroll
        for (int r = 0; r < 4; ++r) {
            float s = lrow[rb][r];
            #pragma unroll
            for (int off = 1; off < 16; off <<= 1)
                s += __shfl_xor(s, off);
            inv[r] = 1.f / s;
        }
        const size_t obase = (size_t)(b * T_SEQ + qbase + rb * 16) * D_MODEL
                             + (size_t)h * HD;
        #pragma unroll
        for (int nt = 0; nt < 4; ++nt)
            #pragma unroll
            for (int r = 0; r < 4; ++r)
                aout[obase + (size_t)(4 * g + r) * D_MODEL + nt * 16 + n]
                    = (__bf16)(o[rb][nt][r] * inv[r]);
    }
}

// ---------------------------------------------------------------------------
extern "C" void kernel_launch(void* const* d_in, const int* in_sizes, int n_in,
                              void* d_out, int out_size, void* d_ws, size_t ws_size,
                              hipStream_t stream)
{
    const float* x      = (const float*)d_in[0];
    const float* w_qkv  = (const float*)d_in[1];
    const float* b_qkv  = (const float*)d_in[2];
    const float* w_proj = (const float*)d_in[3];
    const float* b_proj = (const float*)d_in[4];
    float* out = (float*)d_out;

    char* ws = (char*)d_ws;
    __bf16* qkb    = (__bf16*)ws;                                   // 8192 x 2048
    __bf16* vTb    = qkb + (size_t)M_ROWS * 2048;                   // 64 x 64 x 2048
    __bf16* xb     = vTb + (size_t)NH * B_SZ * HD * T_SEQ;          // 8192 x 1024
    __bf16* wqkvT  = xb + (size_t)M_ROWS * D_MODEL;                 // 3072 x 1024
    __bf16* wprojT = wqkvT + (size_t)N_QKV * D_MODEL;               // 1024 x 1024
    __bf16* aout   = wprojT + (size_t)D_MODEL * D_MODEL;            // 8192 x 1024

    cvt_bf16<<<dim3(M_ROWS * D_MODEL / 8 / 256), 256, 0, stream>>>(
        x, xb, M_ROWS * D_MODEL / 8);
    transpose_cvt<<<dim3(N_QKV / 32, D_MODEL / 32), 256, 0, stream>>>(
        w_qkv, wqkvT, D_MODEL, N_QKV);
    transpose_cvt<<<dim3(D_MODEL / 32, D_MODEL / 32), 256, 0, stream>>>(
        w_proj, wprojT, D_MODEL, D_MODEL);

    gemm_mfma<1><<<dim3((M_ROWS / 128) * (N_QKV / 128)), 256, 0, stream>>>(
        xb, wqkvT, b_qkv, qkb, vTb, M_ROWS, N_QKV, D_MODEL);

    attn_mfma<<<dim3(B_SZ * NH * 16), 256, 0, stream>>>(qkb, vTb, aout);

    gemm_mfma<0><<<dim3((M_ROWS / 128) * (D_MODEL / 128)), 256, 0, stream>>>(
        aout, wprojT, b_proj, out, nullptr, M_ROWS, D_MODEL, D_MODEL);
}

// Round 9
// 193.277 us; speedup vs baseline: 40.6426x; 1.0108x over previous
//
#include <hip/hip_runtime.h>
#include <hip/hip_bf16.h>
#include <math.h>

#define D_MODEL 1024
#define NH      16
#define HD      64
#define T_SEQ   2048
#define B_SZ    4
#define M_ROWS  (B_SZ * T_SEQ)       // 8192
#define N_QKV   (3 * D_MODEL)        // 3072

typedef __bf16 bf16x8 __attribute__((ext_vector_type(8)));
typedef __bf16 bf16x4 __attribute__((ext_vector_type(4)));
typedef float  f32x4  __attribute__((ext_vector_type(4)));

__device__ __forceinline__ bf16x8 cvt8(float4 a, float4 b) {
    bf16x8 v;
    v[0]=(__bf16)a.x; v[1]=(__bf16)a.y; v[2]=(__bf16)a.z; v[3]=(__bf16)a.w;
    v[4]=(__bf16)b.x; v[5]=(__bf16)b.y; v[6]=(__bf16)b.z; v[7]=(__bf16)b.w;
    return v;
}

__device__ __forceinline__ void gload_lds16(const __bf16* g, __bf16* l) {
    __builtin_amdgcn_global_load_lds(
        (const __attribute__((address_space(1))) void*)g,
        (__attribute__((address_space(3))) void*)l, 16, 0, 0);
}

// raw v_exp_f32: computes 2^x (input already in log2 units)
__device__ __forceinline__ float exp2v(float x) {
    float r;
    asm("v_exp_f32 %0, %1" : "=v"(r) : "v"(x));
    return r;
}

// ---------------------------------------------------------------------------
// fp32 -> bf16 elementwise convert
// ---------------------------------------------------------------------------
__global__ __launch_bounds__(256) void cvt_bf16(const float* __restrict__ in,
                                                __bf16* __restrict__ out, int n8)
{
    int i = blockIdx.x * 256 + threadIdx.x;
    if (i < n8) {
        float4 a = ((const float4*)in)[2 * i];
        float4 b = ((const float4*)in)[2 * i + 1];
        ((bf16x8*)out)[i] = cvt8(a, b);
    }
}

// ---------------------------------------------------------------------------
// Transpose + convert: W[R][C] fp32 -> WT[C][R] bf16
// ---------------------------------------------------------------------------
__global__ __launch_bounds__(256) void transpose_cvt(
    const float* __restrict__ W, __bf16* __restrict__ WT, int R, int C)
{
    __shared__ float t[32][33];
    const int tr0 = blockIdx.y * 32, tc0 = blockIdx.x * 32;
    const int lr = threadIdx.x >> 5, lc = threadIdx.x & 31;
    #pragma unroll
    for (int i = 0; i < 4; ++i)
        t[lr + i * 8][lc] = W[(size_t)(tr0 + lr + i * 8) * C + tc0 + lc];
    __syncthreads();
    #pragma unroll
    for (int i = 0; i < 4; ++i)
        WT[(size_t)(tc0 + lr + i * 8) * R + tr0 + lc] = (__bf16)t[lc][lr + i * 8];
}

// ---------------------------------------------------------------------------
// bf16 MFMA GEMM: 128x128 tile, BK=64, 4 waves, 4x4 16x16x32 frags.
// Both-sides XOR swizzle (rule #21): linear LDS dest + inverse-swizzled
// global source + swizzled read.  MODE 0: float C.  MODE 1: qkv split.
// ---------------------------------------------------------------------------
template<int MODE>
__global__ __launch_bounds__(256) void gemm_mfma(
    const __bf16* __restrict__ A, const __bf16* __restrict__ BT,
    const float* __restrict__ bias, void* __restrict__ C0,
    __bf16* __restrict__ vT, int M, int N, int K)
{
    __shared__ __bf16 As[128 * 64];
    __shared__ __bf16 Bs[128 * 64];

    const int nbn = N >> 7;
    const int nwg = gridDim.x;
    int bid = blockIdx.x;
    bid = (bid & 7) * (nwg >> 3) + (bid >> 3);       // XCD swizzle (nwg % 8 == 0)
    const int tm = bid / nbn, tn = bid % nbn;
    const int row0 = tm << 7, col0 = tn << 7;

    const int tid  = threadIdx.x;
    const int wid  = tid >> 6, lane = tid & 63;
    const int wm   = wid >> 1, wn = wid & 1;
    const int g    = lane >> 4, r16 = lane & 15;

    f32x4 acc[4][4] = {};

    for (int k0 = 0; k0 < K; k0 += 64) {
        #pragma unroll
        for (int i = 0; i < 4; ++i) {
            const int seg = wid * 4 + i;                 // 0..15
            const int row = seg * 8 + (lane >> 3);       // 0..127
            const int kel = ((lane & 7) * 8) ^ ((row & 7) * 8);
            gload_lds16(A  + (size_t)(row0 + row) * K + k0 + kel, As + seg * 512);
            gload_lds16(BT + (size_t)(col0 + row) * K + k0 + kel, Bs + seg * 512);
        }
        __syncthreads();

        #pragma unroll
        for (int kk = 0; kk < 2; ++kk) {
            bf16x8 af[4], bfr[4];
            #pragma unroll
            for (int mt = 0; mt < 4; ++mt) {
                const int row = wm * 64 + mt * 16 + r16;
                af[mt] = *(const bf16x8*)((const char*)As + row * 128
                             + ((kk * 64 + g * 16) ^ ((row & 7) << 4)));
            }
            #pragma unroll
            for (int nt = 0; nt < 4; ++nt) {
                const int row = wn * 64 + nt * 16 + r16;
                bfr[nt] = *(const bf16x8*)((const char*)Bs + row * 128
                             + ((kk * 64 + g * 16) ^ ((row & 7) << 4)));
            }
            #pragma unroll
            for (int mt = 0; mt < 4; ++mt)
                #pragma unroll
                for (int nt = 0; nt < 4; ++nt)
                    acc[mt][nt] = __builtin_amdgcn_mfma_f32_16x16x32_bf16(
                        af[mt], bfr[nt], acc[mt][nt], 0, 0, 0);
        }
        __syncthreads();
    }

    const bool isV = (MODE == 1) && (tn >= 16);

    #pragma unroll
    for (int mt = 0; mt < 4; ++mt) {
        #pragma unroll
        for (int nt = 0; nt < 4; ++nt) {
            const int col = col0 + wn * 64 + nt * 16 + r16;
            const float bv = bias[col];
            const int rowb = row0 + wm * 64 + mt * 16 + g * 4;
            if (MODE == 0) {
                #pragma unroll
                for (int j = 0; j < 4; ++j)
                    ((float*)C0)[(size_t)(rowb + j) * N + col] = acc[mt][nt][j] + bv;
            } else if (!isV) {
                #pragma unroll
                for (int j = 0; j < 4; ++j)
                    ((__bf16*)C0)[(size_t)(rowb + j) * 2048 + col] =
                        (__bf16)(acc[mt][nt][j] + bv);
            } else {
                const int hh = (col - 2048) >> 6, dd = (col - 2048) & 63;
                const int bb = rowb >> 11, tt = rowb & 2047;
                __bf16 p4[4];
                #pragma unroll
                for (int j = 0; j < 4; ++j) p4[j] = (__bf16)(acc[mt][nt][j] + bv);
                *(bf16x4*)&vT[((size_t)((bb * NH + hh) * HD + dd)) * T_SEQ + tt]
                    = *(const bf16x4*)p4;
            }
        }
    }
}

// ---------------------------------------------------------------------------
// MFMA flash attention v3.2 (reverted R7 structure + CU-balanced dispatch +
// fully-masked-tile skip).
// Block = 4 waves = one 128-row q-strip; wave owns 32 q-rows.  Grid 1024;
// qt slot-groups {15,8,4,3},{14,9,5,2},{13,10,6,1},{12,11,7,0} each sum to
// exactly 68 k-tiles -> balanced CU load.  Defer-max (log2 units) + exp2.
// K/V/P LDS swizzled byte^=((row&7)<<4).
// ---------------------------------------------------------------------------
__global__ __launch_bounds__(256) void attn_mfma(
    const __bf16* __restrict__ qkb, const __bf16* __restrict__ vT,
    __bf16* __restrict__ aout)
{
    const int idx  = blockIdx.x;            // 0..1023
    const int slot = idx >> 6;
    const int j    = slot & 3, p = slot >> 2;
    const int qt   = (p == 0) ? 15 - j : (p == 1) ? 8 + j : (p == 2) ? 4 + j : 3 - j;
    const int bh   = idx & 63;
    const int b    = bh >> 4;
    const int h    = bh & 15;
    const int tid  = threadIdx.x;
    const int wid  = tid >> 6;
    const int lane = tid & 63;
    const int g    = lane >> 4;
    const int n    = lane & 15;
    const int swzn = (n & 7) << 4;

    const int q0    = qt * 128;
    const int qbase = q0 + wid * 32;
    const int nkt   = 2 * qt + 2;

    __shared__ __align__(16) char Ks[64 * 128];        // [kv][d]
    __shared__ __align__(16) char Vs[64 * 128];        // [d][kv]
    __shared__ __align__(16) char Ps[4][32 * 128];     // per-wave [q][kv]

    const int srow = tid >> 2;              // 0..63
    const int sb0  = (tid & 3) << 4;        // byte slot 0,16,32,48
    const int swzw = (srow & 7) << 4;
    const int sd8  = (tid & 3) * 8;

    // ---- Q fragments: scale 1/8 * log2(e) folded in ----
    const float qscale = 0.125f * 1.44269504089f;
    bf16x8 qa[2][2];
    #pragma unroll
    for (int rb = 0; rb < 2; ++rb) {
        const size_t qrow = (size_t)(b * T_SEQ + qbase + rb * 16 + n) * 2048
                            + (size_t)h * HD;
        qa[rb][0] = *(const bf16x8*)&qkb[qrow + g * 8];
        qa[rb][1] = *(const bf16x8*)&qkb[qrow + 32 + g * 8];
        #pragma unroll
        for (int jj = 0; jj < 8; ++jj) {
            qa[rb][0][jj] = (__bf16)((float)qa[rb][0][jj] * qscale);
            qa[rb][1][jj] = (__bf16)((float)qa[rb][1][jj] * qscale);
        }
    }

    f32x4 o[2][4] = {};
    float mrow[2][4] = {};                  // defer-max base m=0 (log2 units)
    float lrow[2][4] = {};                  // lane-partial row sums

    const __bf16* gK = qkb + (size_t)(b * T_SEQ + srow) * 2048 + 1024
                       + (size_t)h * HD + sd8;
    const __bf16* gV = vT + ((size_t)((b * NH + h) * HD + srow)) * T_SEQ + sd8;

    bf16x8 kreg0 = *(const bf16x8*)gK;
    bf16x8 kreg1 = *(const bf16x8*)(gK + 32);
    bf16x8 vreg0 = *(const bf16x8*)gV;
    bf16x8 vreg1 = *(const bf16x8*)(gV + 32);

    for (int kt = 0; kt < nkt; ++kt) {
        *(bf16x8*)(Ks + srow * 128 + (sb0 ^ swzw))        = kreg0;
        *(bf16x8*)(Ks + srow * 128 + ((sb0 + 64) ^ swzw)) = kreg1;
        *(bf16x8*)(Vs + srow * 128 + (sb0 ^ swzw))        = vreg0;
        *(bf16x8*)(Vs + srow * 128 + ((sb0 + 64) ^ swzw)) = vreg1;
        __syncthreads();

        if (kt + 1 < nkt) {
            const size_t kb2 = (size_t)(kt + 1) * 64;
            kreg0 = *(const bf16x8*)(gK + kb2 * 2048);
            kreg1 = *(const bf16x8*)(gK + kb2 * 2048 + 32);
            vreg0 = *(const bf16x8*)(gV + kb2);
            vreg1 = *(const bf16x8*)(gV + kb2 + 32);
        }

        const int kb0 = kt * 64;
        const bool active = (kb0 <= qbase + 31);    // wave-uniform: any unmasked kv?

        if (active) {
            // ---- S = Q K^T (log2 units) ----
            f32x4 s4[2][4] = {};
            __builtin_amdgcn_s_setprio(1);
            #pragma unroll
            for (int cc = 0; cc < 2; ++cc) {
                bf16x8 kf[4];
                #pragma unroll
                for (int sub = 0; sub < 4; ++sub)
                    kf[sub] = *(const bf16x8*)(Ks + (sub * 16 + n) * 128
                                               + ((cc * 64 + g * 16) ^ swzn));
                #pragma unroll
                for (int rb = 0; rb < 2; ++rb)
                    #pragma unroll
                    for (int sub = 0; sub < 4; ++sub)
                        s4[rb][sub] = __builtin_amdgcn_mfma_f32_16x16x32_bf16(
                            qa[rb][cc], kf[sub], s4[rb][sub], 0, 0, 0);
            }
            __builtin_amdgcn_s_setprio(0);

            const bool needmask = (kb0 + 63 > qbase);   // wave-uniform

            #pragma unroll
            for (int rb = 0; rb < 2; ++rb) {
                if (needmask) {
                    #pragma unroll
                    for (int r = 0; r < 4; ++r) {
                        const int qrow = qbase + rb * 16 + 4 * g + r;
                        #pragma unroll
                        for (int sub = 0; sub < 4; ++sub)
                            if (kb0 + sub * 16 + n > qrow) s4[rb][sub][r] = -INFINITY;
                    }
                }
                float pm[4];
                int ok = 1;
                #pragma unroll
                for (int r = 0; r < 4; ++r) {
                    pm[r] = fmaxf(fmaxf(s4[rb][0][r], s4[rb][1][r]),
                                  fmaxf(s4[rb][2][r], s4[rb][3][r]));
                    ok &= (pm[r] <= mrow[rb][r] + 8.f);
                }
                if (__all(ok)) {
                    // fast path: no max-reduce, no rescale, lane-partial sum
                    #pragma unroll
                    for (int r = 0; r < 4; ++r) {
                        const float m = mrow[rb][r];
                        const float p0 = exp2v(s4[rb][0][r] - m);
                        const float p1 = exp2v(s4[rb][1][r] - m);
                        const float p2 = exp2v(s4[rb][2][r] - m);
                        const float p3 = exp2v(s4[rb][3][r] - m);
                        lrow[rb][r] += (p0 + p1) + (p2 + p3);
                        char* prow = Ps[wid] + (rb * 16 + 4 * g + r) * 128;
                        const int pswz = ((4 * g + r) & 7) << 4;
                        *(__bf16*)(prow + ((2 * n)      ^ pswz)) = (__bf16)p0;
                        *(__bf16*)(prow + ((2 * n + 32) ^ pswz)) = (__bf16)p1;
                        *(__bf16*)(prow + ((2 * n + 64) ^ pswz)) = (__bf16)p2;
                        *(__bf16*)(prow + ((2 * n + 96) ^ pswz)) = (__bf16)p3;
                    }
                } else {
                    // slow path: butterfly max, rescale o and partial lrow
                    #pragma unroll
                    for (int r = 0; r < 4; ++r) {
                        float tm = pm[r];
                        #pragma unroll
                        for (int off = 1; off < 16; off <<= 1)
                            tm = fmaxf(tm, __shfl_xor(tm, off));
                        const float mnew = fmaxf(mrow[rb][r], tm);
                        const float corr = exp2v(mrow[rb][r] - mnew);
                        mrow[rb][r] = mnew;
                        const float p0 = exp2v(s4[rb][0][r] - mnew);
                        const float p1 = exp2v(s4[rb][1][r] - mnew);
                        const float p2 = exp2v(s4[rb][2][r] - mnew);
                        const float p3 = exp2v(s4[rb][3][r] - mnew);
                        lrow[rb][r] = lrow[rb][r] * corr + (p0 + p1) + (p2 + p3);
                        #pragma unroll
                        for (int nt = 0; nt < 4; ++nt) o[rb][nt][r] *= corr;
                        char* prow = Ps[wid] + (rb * 16 + 4 * g + r) * 128;
                        const int pswz = ((4 * g + r) & 7) << 4;
                        *(__bf16*)(prow + ((2 * n)      ^ pswz)) = (__bf16)p0;
                        *(__bf16*)(prow + ((2 * n + 32) ^ pswz)) = (__bf16)p1;
                        *(__bf16*)(prow + ((2 * n + 64) ^ pswz)) = (__bf16)p2;
                        *(__bf16*)(prow + ((2 * n + 96) ^ pswz)) = (__bf16)p3;
                    }
                }
            }

            // ---- O += P V ----
            __builtin_amdgcn_s_setprio(1);
            #pragma unroll
            for (int cc = 0; cc < 2; ++cc) {
                bf16x8 vf[4];
                #pragma unroll
                for (int nt = 0; nt < 4; ++nt)
                    vf[nt] = *(const bf16x8*)(Vs + (nt * 16 + n) * 128
                                              + ((cc * 64 + g * 16) ^ swzn));
                #pragma unroll
                for (int rb = 0; rb < 2; ++rb) {
                    bf16x8 pa = *(const bf16x8*)(Ps[wid] + (rb * 16 + n) * 128
                                                 + ((cc * 64 + g * 16) ^ swzn));
                    #pragma unroll
                    for (int nt = 0; nt < 4; ++nt)
                        o[rb][nt] = __builtin_amdgcn_mfma_f32_16x16x32_bf16(
                            pa, vf[nt], o[rb][nt], 0, 0, 0);
                }
            }
            __builtin_amdgcn_s_setprio(0);
        }
        __syncthreads();
    }

    // ---- final 16-lane reduce of lrow, normalize, store ----
    #pragma unroll
    for (int rb = 0; rb < 2; ++rb) {
        float inv[4];
        #pragma unroll
        for (int r = 0; r < 4; ++r) {
            float s = lrow[rb][r];
            #pragma unroll
            for (int off = 1; off < 16; off <<= 1)
                s += __shfl_xor(s, off);
            inv[r] = 1.f / s;
        }
        const size_t obase = (size_t)(b * T_SEQ + qbase + rb * 16) * D_MODEL
                             + (size_t)h * HD;
        #pragma unroll
        for (int nt = 0; nt < 4; ++nt)
            #pragma unroll
            for (int r = 0; r < 4; ++r)
                aout[obase + (size_t)(4 * g + r) * D_MODEL + nt * 16 + n]
                    = (__bf16)(o[rb][nt][r] * inv[r]);
    }
}

// ---------------------------------------------------------------------------
extern "C" void kernel_launch(void* const* d_in, const int* in_sizes, int n_in,
                              void* d_out, int out_size, void* d_ws, size_t ws_size,
                              hipStream_t stream)
{
    const float* x      = (const float*)d_in[0];
    const float* w_qkv  = (const float*)d_in[1];
    const float* b_qkv  = (const float*)d_in[2];
    const float* w_proj = (const float*)d_in[3];
    const float* b_proj = (const float*)d_in[4];
    float* out = (float*)d_out;

    char* ws = (char*)d_ws;
    __bf16* qkb    = (__bf16*)ws;                                   // 8192 x 2048
    __bf16* vTb    = qkb + (size_t)M_ROWS * 2048;                   // 64 x 64 x 2048
    __bf16* xb     = vTb + (size_t)NH * B_SZ * HD * T_SEQ;          // 8192 x 1024
    __bf16* wqkvT  = xb + (size_t)M_ROWS * D_MODEL;                 // 3072 x 1024
    __bf16* wprojT = wqkvT + (size_t)N_QKV * D_MODEL;               // 1024 x 1024
    __bf16* aout   = wprojT + (size_t)D_MODEL * D_MODEL;            // 8192 x 1024

    cvt_bf16<<<dim3(M_ROWS * D_MODEL / 8 / 256), 256, 0, stream>>>(
        x, xb, M_ROWS * D_MODEL / 8);
    transpose_cvt<<<dim3(N_QKV / 32, D_MODEL / 32), 256, 0, stream>>>(
        w_qkv, wqkvT, D_MODEL, N_QKV);
    transpose_cvt<<<dim3(D_MODEL / 32, D_MODEL / 32), 256, 0, stream>>>(
        w_proj, wprojT, D_MODEL, D_MODEL);

    gemm_mfma<1><<<dim3((M_ROWS / 128) * (N_QKV / 128)), 256, 0, stream>>>(
        xb, wqkvT, b_qkv, qkb, vTb, M_ROWS, N_QKV, D_MODEL);

    attn_mfma<<<dim3(B_SZ * NH * 16), 256, 0, stream>>>(qkb, vTb, aout);

    gemm_mfma<0><<<dim3((M_ROWS / 128) * (D_MODEL / 128)), 256, 0, stream>>>(
        aout, wprojT, b_proj, out, nullptr, M_ROWS, D_MODEL, D_MODEL);
}